// Round 2
// baseline (278.063 us; speedup 1.0000x reference)
//
#include <hip/hip_runtime.h>
#include <float.h>

typedef unsigned short ushort_t;
typedef unsigned int uint_t;

// Problem constants
#define NROWS 16384   // 8*2048
#define DDIM  768
#define KCODES 2048
#define MARGIN 8e-4f

// bf16 helpers (RNE)
__device__ __forceinline__ ushort_t f2bf(float x) {
    uint_t u = __float_as_uint(x);
    uint_t r = (u + 0x7fffu + ((u >> 16) & 1u)) >> 16;
    return (ushort_t)r;
}

// monotonic float<->uint encoding for LDS atomicMin on floats
__device__ __forceinline__ uint_t fenc(float f) {
    uint_t u = __float_as_uint(f);
    return (u & 0x80000000u) ? ~u : (u | 0x80000000u);
}
__device__ __forceinline__ float fdec(uint_t k) {
    uint_t u = (k & 0x80000000u) ? (k ^ 0x80000000u) : ~k;
    return __uint_as_float(u);
}

typedef __attribute__((ext_vector_type(8))) short bf16x8;
typedef __attribute__((ext_vector_type(8))) unsigned short ushort8;
typedef __attribute__((ext_vector_type(4))) float f32x4;

__device__ __forceinline__ int swz(int r) { return (r & 3) ^ ((r >> 2) & 3); }

// ---------- prep2: ee (exact, same order as before) + Eh bf16 + zero loss --
__global__ void prep2_kernel(const float* __restrict__ emb, float* __restrict__ ee,
                             ushort_t* __restrict__ Eh, float* __restrict__ out_loss) {
    const int c = blockIdx.x, t = threadIdx.x;
    if (c == 0 && t == 0) out_loss[0] = 0.f;
    const float* e = emb + (size_t)c * DDIM;
    float s = 0.f;
    for (int i = t; i < DDIM; i += 256) { float v = e[i]; s += v * v; }
    for (int off = 32; off; off >>= 1) s += __shfl_down(s, off);
    __shared__ float red[4];
    if ((t & 63) == 0) red[t >> 6] = s;
    __syncthreads();
    if (t == 0) ee[c] = red[0] + red[1] + red[2] + red[3];
    if (t < 192) {
        const float4 v = ((const float4*)e)[t];
        ushort4 h;
        h.x = f2bf(v.x); h.y = f2bf(v.y); h.z = f2bf(v.z); h.w = f2bf(v.w);
        ((ushort4*)(Eh + (size_t)c * DDIM))[t] = h;
    }
}

// ------- fused2: per-step A convert + proven 64x128-wave GEMM + argmin -----
// Block: 64 rows, 256 threads (4 waves), wavegrid 1x4 -> wave tile 64x128.
// Chunk loop: 4 chunks of 512 codes. Two-sync single-buffer staging (round-0
// proven structure). A tile 64x32 bf16 (4KB, reg-staged convert from z f32),
// B tile 512x32 bf16 (32KB, global_load_lds from Eh, pre-swizzled source).
#define R      64
#define CCH    512
#define NCH    4            // 2048/512
#define KST    24           // 768/32
#define CAP    16
#define B_OFF    4096
#define RMIN_OFF 36864
#define RCNT_OFF 37120
#define SVAL_OFF 37376
#define SIDX_OFF 41472
#define LRED_OFF 45568
#define SMEM_SZ  45600

__global__ __launch_bounds__(256, 2)
void fused2_kernel(const float* __restrict__ z, const float* __restrict__ emb,
                   const ushort_t* __restrict__ Eh, const float* __restrict__ ee,
                   float* __restrict__ ids_f32, float* __restrict__ out0,
                   float* __restrict__ out_loss) {
    __shared__ __align__(16) char smem[SMEM_SZ];
    uint_t* rowminU = (uint_t*)(smem + RMIN_OFF);
    int*    rcnt    = (int*)(smem + RCNT_OFF);
    float (*sval)[CAP] = (float(*)[CAP])(smem + SVAL_OFF);
    int   (*sidx)[CAP] = (int(*)[CAP])(smem + SIDX_OFF);
    float*  lred    = (float*)(smem + LRED_OFF);

    const int t = threadIdx.x;
    const int w = t >> 6, l = t & 63;
    const int row0 = blockIdx.x * R;

    if (t < 64) { rowminU[t] = 0xFFFFFFFFu; rcnt[t] = 0; }

    // ---- A conversion mapping: thread -> (row, 8-elem K-sub-slot)
    const int arow = t >> 2, acs = t & 3;
    const float* zA = z + (size_t)(row0 + arow) * DDIM + acs * 8;
    char* aw = smem + (arow << 6) + ((acs ^ swz(arow)) << 4);

    // ---- B staging: LDS dest linear, global source pre-swizzled
    const int sri = l >> 2, slot = l & 3;
    const int swzs = swz(sri);                 // swz(row) depends only on row%16
    const int brow = w * 128 + sri;
    const uint_t lB = B_OFF + (uint_t)(w * 8192);

    // ---- fragment LDS byte offsets
    const int g = l >> 4, lr = l & 15;
    int aoff[4], boff[8];
    #pragma unroll
    for (int mi = 0; mi < 4; ++mi) {
        const int r = mi * 16 + lr;
        aoff[mi] = (r << 6) + ((g ^ swz(r)) << 4);
    }
    #pragma unroll
    for (int ni = 0; ni < 8; ++ni) {
        const int rb = w * 128 + ni * 16 + lr;
        boff[ni] = B_OFF + (rb << 6) + ((g ^ swz(rb)) << 4);
    }

    f32x4 acc[4][8];
    for (int c = 0; c < NCH; ++c) {
        const int c0 = c * CCH;
        #pragma unroll
        for (int mi = 0; mi < 4; ++mi)
            #pragma unroll
            for (int ni = 0; ni < 8; ++ni) acc[mi][ni] = (f32x4){0.f, 0.f, 0.f, 0.f};

        const ushort_t* gB = Eh + (size_t)(c0 + brow) * DDIM + ((slot ^ swzs) << 3);

        for (int s = 0; s < KST; ++s) {
            __syncthreads();                    // prior tile reads done
            #pragma unroll
            for (int q = 0; q < 8; ++q)
                __builtin_amdgcn_global_load_lds(
                    (const __attribute__((address_space(1))) void*)(gB + q * (16 * DDIM)),
                    (__attribute__((address_space(3))) void*)(smem + lB + q * 1024),
                    16, 0, 0);
            {   // A: f32 -> bf16 reg-staged convert into swizzled 4KB tile
                const float4 v0 = *(const float4*)(zA + 32 * s);
                const float4 v1 = *(const float4*)(zA + 32 * s + 4);
                ushort8 h;
                h[0] = f2bf(v0.x); h[1] = f2bf(v0.y); h[2] = f2bf(v0.z); h[3] = f2bf(v0.w);
                h[4] = f2bf(v1.x); h[5] = f2bf(v1.y); h[6] = f2bf(v1.z); h[7] = f2bf(v1.w);
                *(ushort8*)aw = h;
            }
            gB += 32;
            __syncthreads();                    // drains vmcnt + lgkm: tiles ready

            bf16x8 af[4], bfr[8];
            #pragma unroll
            for (int mi = 0; mi < 4; ++mi) af[mi] = *(const bf16x8*)(smem + aoff[mi]);
            #pragma unroll
            for (int ni = 0; ni < 8; ++ni) bfr[ni] = *(const bf16x8*)(smem + boff[ni]);
            #pragma unroll
            for (int mi = 0; mi < 4; ++mi)
                #pragma unroll
                for (int ni = 0; ni < 8; ++ni)
                    acc[mi][ni] = __builtin_amdgcn_mfma_f32_16x16x32_bf16(
                        af[mi], bfr[ni], acc[mi][ni], 0, 0, 0);
        }

        // ---- chunk epilogue: d~ = ee - 2*dot~, running row-min + candidates
        float ecv[8];
        #pragma unroll
        for (int ni = 0; ni < 8; ++ni) ecv[ni] = ee[c0 + w * 128 + ni * 16 + lr];
        #pragma unroll
        for (int mi = 0; mi < 4; ++mi)
            #pragma unroll
            for (int ni = 0; ni < 8; ++ni)
                #pragma unroll
                for (int r = 0; r < 4; ++r)
                    acc[mi][ni][r] = ecv[ni] - 2.0f * acc[mi][ni][r];

        #pragma unroll
        for (int mi = 0; mi < 4; ++mi)
            #pragma unroll
            for (int r = 0; r < 4; ++r) {
                float v = acc[mi][0][r];
                #pragma unroll
                for (int ni = 1; ni < 8; ++ni) v = fminf(v, acc[mi][ni][r]);
                v = fminf(v, __shfl_xor(v, 1));
                v = fminf(v, __shfl_xor(v, 2));
                v = fminf(v, __shfl_xor(v, 4));
                v = fminf(v, __shfl_xor(v, 8));
                if (lr == 0) atomicMin(&rowminU[mi * 16 + g * 4 + r], fenc(v));
            }
        __syncthreads();
        #pragma unroll
        for (int mi = 0; mi < 4; ++mi)
            #pragma unroll
            for (int r = 0; r < 4; ++r) {
                const int lrow = mi * 16 + g * 4 + r;
                const float lim = fdec(rowminU[lrow]) + MARGIN;   // running min
                #pragma unroll
                for (int ni = 0; ni < 8; ++ni) {
                    const float vv = acc[mi][ni][r];
                    if (vv <= lim) {
                        const int p = atomicAdd(&rcnt[lrow], 1);
                        if (p < CAP) {
                            sval[lrow][p] = vv;
                            sidx[lrow][p] = c0 + w * 128 + ni * 16 + lr;
                        }
                    }
                }
            }
        // next chunk's first __syncthreads orders these LDS ops vs restaging
    }
    __syncthreads();   // all appends visible

    // ---- final: exact zz + fp32 recheck + gather + straight-through + loss
    float wloss = 0.f;
    for (int rr = 0; rr < 16; ++rr) {
        const int lrow = w * 16 + rr;
        const int row = row0 + lrow;
        const float* zr = z + (size_t)row * DDIM;

        float szz = 0.f;
        #pragma unroll
        for (int k = 0; k < 12; ++k) { const float v = zr[l + 64 * k]; szz += v * v; }
        for (int off = 32; off; off >>= 1) szz += __shfl_down(szz, off);
        const float zzr = __shfl(szz, 0);

        const float T = fdec(rowminU[lrow]) + MARGIN;
        const int n = rcnt[lrow] < CAP ? rcnt[lrow] : CAP;
        float val = FLT_MAX; int idx = 0x7fffffff;
        if (l < n) { val = sval[lrow][l]; idx = sidx[lrow][l]; }
        unsigned long long m = __ballot(val <= T);

        float bestd = FLT_MAX; int besti = 0x7fffffff;
        while (m) {
            const int j = __ffsll(m) - 1; m &= m - 1;
            const int cand = __shfl(idx, j);
            const float* er = emb + (size_t)cand * DDIM;
            float p = 0.f;
            #pragma unroll
            for (int k = 0; k < 12; ++k) p += zr[l + 64 * k] * er[l + 64 * k];
            for (int off = 32; off; off >>= 1) p += __shfl_down(p, off);
            if (l == 0) {
                const float t1 = zzr + ee[cand];        // fp32 round (ref order)
                const float d  = t1 - 2.0f * p;         // fp32 round
                if (d < bestd || (d == bestd && cand < besti)) { bestd = d; besti = cand; }
            }
        }
        const int bi = __shfl(besti, 0);
        if (l == 0) ids_f32[row] = (float)bi;

        const float4* zr4 = (const float4*)zr;
        const float4* er4 = (const float4*)(emb + (size_t)bi * DDIM);
        float4* o4 = (float4*)(out0 + (size_t)row * DDIM);
        float s = 0.f;
        #pragma unroll
        for (int j2 = 0; j2 < 3; ++j2) {
            const int i4 = l + 64 * j2;
            const float4 zv = zr4[i4];
            const float4 ev = er4[i4];
            float4 o;
            o.x = zv.x + (ev.x - zv.x); o.y = zv.y + (ev.y - zv.y);
            o.z = zv.z + (ev.z - zv.z); o.w = zv.w + (ev.w - zv.w);
            o4[i4] = o;
            const float dx = zv.x - ev.x, dy = zv.y - ev.y;
            const float dz = zv.z - ev.z, dw = zv.w - ev.w;
            s += dx * dx + dy * dy + dz * dz + dw * dw;
        }
        for (int off = 32; off; off >>= 1) s += __shfl_down(s, off);
        if (l == 0) wloss += s;
    }
    if (l == 0) lred[w] = wloss;
    __syncthreads();
    if (t == 0) {
        float tot = lred[0] + lred[1] + lred[2] + lred[3];
        atomicAdd(out_loss, tot * (0.25f / (float)((size_t)NROWS * DDIM)));
    }
}

// ================= Fallback (round-3 exact fp32 path, proven) ==============
__global__ void ee_kernel(const float* __restrict__ emb, float* __restrict__ ee) {
    int c = blockIdx.x;
    const float* e = emb + (size_t)c * DDIM;
    int t = threadIdx.x;
    float s = 0.f;
    for (int i = t; i < DDIM; i += 256) { float v = e[i]; s += v * v; }
    for (int off = 32; off; off >>= 1) s += __shfl_down(s, off);
    __shared__ float red[4];
    if ((t & 63) == 0) red[t >> 6] = s;
    __syncthreads();
    if (t == 0) ee[c] = red[0] + red[1] + red[2] + red[3];
}

__global__ void zz_kernel(const float* __restrict__ z, float* __restrict__ zz) {
    const int t = threadIdx.x;
    const int row = blockIdx.x * 4 + (t >> 6);
    const int lane = t & 63;
    const float* zr = z + (size_t)row * DDIM;
    float s = 0.f;
    for (int i = lane; i < DDIM; i += 64) { float v = zr[i]; s += v * v; }
    for (int off = 32; off; off >>= 1) s += __shfl_down(s, off);
    if (lane == 0) zz[row] = s;
}

#define BM 32
#define BN 128
#define BKS 32
#define SPLITC 2
#define CODES_PER_BLOCK (KCODES / SPLITC)
#define NCHUNK (CODES_PER_BLOCK / BN)
#define NSTAGE (DDIM / BKS)
#define APADR 33
#define BPADC 132

__global__ __launch_bounds__(256)
void argmin_kernel(const float* __restrict__ z, const float* __restrict__ emb,
                   const float* __restrict__ ee, const float* __restrict__ zz,
                   float* __restrict__ pval, int* __restrict__ pidx) {
    __shared__ float Af[BKS][APADR];
    __shared__ float Bf[BKS][BPADC];
    __shared__ float cval[BM][33];
    __shared__ int   cidx[BM][33];
    __shared__ float zzs[BM];
    const int t = threadIdx.x;
    const int part = blockIdx.x & (SPLITC - 1);
    const int rb = blockIdx.x >> 1;
    const int row0 = rb * BM;
    const int cbase = part * CODES_PER_BLOCK;
    const int tx = t & 31, ty = t >> 5;
    const int sr = t >> 3;
    const int sk = 4 * (t & 7);
    if (t < BM) zzs[t] = zz[row0 + t];
    float bv[4]; int bi[4];
    #pragma unroll
    for (int i = 0; i < 4; ++i) { bv[i] = FLT_MAX; bi[i] = 0x7fffffff; }
    const float* zt = z + (size_t)(row0 + sr) * DDIM;
    for (int chunk = 0; chunk < NCHUNK; ++chunk) {
        const int c0 = cbase + chunk * BN;
        const float* ebase = emb + (size_t)(c0 + sr) * DDIM;
        float acc[4][4];
        #pragma unroll
        for (int i = 0; i < 4; ++i)
            #pragma unroll
            for (int j = 0; j < 4; ++j) acc[i][j] = 0.f;
        float4 pa = *(const float4*)&zt[sk];
        float4 pb[4];
        #pragma unroll
        for (int m = 0; m < 4; ++m) pb[m] = *(const float4*)&ebase[(size_t)(32 * m) * DDIM + sk];
        for (int s = 0; s < NSTAGE; ++s) {
            __syncthreads();
            Af[sk + 0][sr] = pa.x; Af[sk + 1][sr] = pa.y;
            Af[sk + 2][sr] = pa.z; Af[sk + 3][sr] = pa.w;
            #pragma unroll
            for (int m = 0; m < 4; ++m) {
                Bf[sk + 0][sr + 32 * m] = pb[m].x;
                Bf[sk + 1][sr + 32 * m] = pb[m].y;
                Bf[sk + 2][sr + 32 * m] = pb[m].z;
                Bf[sk + 3][sr + 32 * m] = pb[m].w;
            }
            __syncthreads();
            if (s + 1 < NSTAGE) {
                const int k1 = (s + 1) * BKS + sk;
                pa = *(const float4*)&zt[k1];
                #pragma unroll
                for (int m = 0; m < 4; ++m)
                    pb[m] = *(const float4*)&ebase[(size_t)(32 * m) * DDIM + k1];
            }
            #pragma unroll
            for (int kk = 0; kk < BKS; ++kk) {
                const float4 a4 = *(const float4*)&Af[kk][4 * ty];
                const float4 b4 = *(const float4*)&Bf[kk][4 * tx];
                const float aa[4] = {a4.x, a4.y, a4.z, a4.w};
                const float bb[4] = {b4.x, b4.y, b4.z, b4.w};
                #pragma unroll
                for (int i = 0; i < 4; ++i)
                    #pragma unroll
                    for (int j = 0; j < 4; ++j) acc[i][j] += aa[i] * bb[j];
            }
        }
        const float4 e4 = *(const float4*)&ee[c0 + 4 * tx];
        const float eev[4] = {e4.x, e4.y, e4.z, e4.w};
        #pragma unroll
        for (int i = 0; i < 4; ++i) {
            const float zzr = zzs[4 * ty + i];
            #pragma unroll
            for (int j = 0; j < 4; ++j) {
                const int code = c0 + 4 * tx + j;
                const float t1 = zzr + eev[j];
                const float d  = t1 - 2.0f * acc[i][j];
                if (d < bv[i] || (d == bv[i] && code < bi[i])) { bv[i] = d; bi[i] = code; }
            }
        }
    }
    __syncthreads();
    #pragma unroll
    for (int i = 0; i < 4; ++i) { cval[4 * ty + i][tx] = bv[i]; cidx[4 * ty + i][tx] = bi[i]; }
    __syncthreads();
    if (t < BM) {
        float v = FLT_MAX; int id = 0x7fffffff;
        #pragma unroll
        for (int x = 0; x < 32; ++x) {
            const float cv = cval[t][x]; const int ci = cidx[t][x];
            if (cv < v || (cv == v && ci < id)) { v = cv; id = ci; }
        }
        pval[part * NROWS + row0 + t] = v;
        pidx[part * NROWS + row0 + t] = id;
    }
}

__global__ void combine_kernel(const float* __restrict__ pval, const int* __restrict__ pidx,
                               float* __restrict__ ids_f32) {
    const int r = blockIdx.x * 256 + threadIdx.x;
    float v = pval[r];           int id = pidx[r];
    const float v1 = pval[NROWS + r]; const int i1 = pidx[NROWS + r];
    if (v1 < v || (v1 == v && i1 < id)) { v = v1; id = i1; }
    ids_f32[r] = (float)id;
}

__global__ __launch_bounds__(256)
void gather_kernel(const float* __restrict__ z, const float* __restrict__ emb,
                   const float* __restrict__ ids_f32, float* __restrict__ out0,
                   float* __restrict__ part) {
    const int b = blockIdx.x;
    const int t = threadIdx.x;
    const int rl = t >> 4, c = t & 15;
    __shared__ int ids[16];
    if (t < 16) ids[t] = (int)ids_f32[b * 16 + t];
    __syncthreads();
    const int row = b * 16 + rl;
    const float4* zr = (const float4*)(z + (size_t)row * DDIM);
    float4* orow = (float4*)(out0 + (size_t)row * DDIM);
    const float4* er = (const float4*)(emb + (size_t)ids[rl] * DDIM);
    float s = 0.f;
    #pragma unroll
    for (int j = 0; j < 12; ++j) {
        const int i4 = c + 16 * j;
        const float4 zv = zr[i4];
        const float4 ev = er[i4];
        float4 o;
        o.x = zv.x + (ev.x - zv.x); o.y = zv.y + (ev.y - zv.y);
        o.z = zv.z + (ev.z - zv.z); o.w = zv.w + (ev.w - zv.w);
        orow[i4] = o;
        float dx = zv.x - ev.x, dy = zv.y - ev.y, dz = zv.z - ev.z, dw = zv.w - ev.w;
        s += dx * dx + dy * dy + dz * dz + dw * dw;
    }
    for (int off = 32; off; off >>= 1) s += __shfl_down(s, off);
    __shared__ float red[4];
    if ((t & 63) == 0) red[t >> 6] = s;
    __syncthreads();
    if (t == 0) part[b] = red[0] + red[1] + red[2] + red[3];
}

__global__ void loss_kernel(const float* __restrict__ part, float* __restrict__ out_loss) {
    const int t = threadIdx.x;
    double s = 0.0;
    for (int i = t; i < 1024; i += 256) s += (double)part[i];
    for (int off = 32; off; off >>= 1) s += __shfl_down(s, off);
    __shared__ double red[4];
    if ((t & 63) == 0) red[t >> 6] = s;
    __syncthreads();
    if (t == 0) {
        const double total = red[0] + red[1] + red[2] + red[3];
        out_loss[0] = (float)(0.25 * (total / (double)((size_t)NROWS * DDIM)));
    }
}

// ================= launch ==================================================
#define EE_OFF   0
#define ZZ_OFF   8192
#define EH_OFF   73728
#define WS_NEED  (EH_OFF + (size_t)KCODES * DDIM * 2)       // ~3.2 MB
#define PART_OFF 73728                                      // fallback (exclusive)
#define PV_OFF   81920

extern "C" void kernel_launch(void* const* d_in, const int* in_sizes, int n_in,
                              void* d_out, int out_size, void* d_ws, size_t ws_size,
                              hipStream_t stream) {
    const float* z   = (const float*)d_in[0];
    const float* emb = (const float*)d_in[1];

    float* out0     = (float*)d_out;
    float* out_ids  = out0 + (size_t)NROWS * DDIM;
    float* out_loss = out_ids + NROWS;

    char* ws = (char*)d_ws;
    float* ee   = (float*)(ws + EE_OFF);
    float* zzws = (float*)(ws + ZZ_OFF);

    if (ws_size >= WS_NEED) {
        ushort_t* Eh = (ushort_t*)(ws + EH_OFF);
        prep2_kernel<<<KCODES, 256, 0, stream>>>(emb, ee, Eh, out_loss);
        fused2_kernel<<<NROWS / R, 256, 0, stream>>>(z, emb, Eh, ee,
                                                     out_ids, out0, out_loss);
    } else {
        float* part = (float*)(ws + PART_OFF);
        float* pval = (float*)(ws + PV_OFF);
        int*   pidx = (int*)(ws + PV_OFF + 131072);
        ee_kernel<<<KCODES, 256, 0, stream>>>(emb, ee);
        zz_kernel<<<NROWS / 4, 256, 0, stream>>>(z, zzws);
        argmin_kernel<<<(NROWS / BM) * SPLITC, 256, 0, stream>>>(z, emb, ee, zzws, pval, pidx);
        combine_kernel<<<NROWS / 256, 256, 0, stream>>>(pval, pidx, out_ids);
        gather_kernel<<<NROWS / 16, 256, 0, stream>>>(z, emb, out_ids, out0, part);
        loss_kernel<<<1, 256, 0, stream>>>(part, out_loss);
    }
}

// Round 3
// 242.885 us; speedup vs baseline: 1.1448x; 1.1448x over previous
//
#include <hip/hip_runtime.h>
#include <float.h>

typedef unsigned short ushort_t;
typedef unsigned int uint_t;

// Problem constants
#define NROWS 16384   // 8*2048
#define DDIM  768
#define KCODES 2048
#define MARGIN 8e-4f

// bf16 helpers (RNE)
__device__ __forceinline__ ushort_t f2bf(float x) {
    uint_t u = __float_as_uint(x);
    uint_t r = (u + 0x7fffu + ((u >> 16) & 1u)) >> 16;
    return (ushort_t)r;
}

// monotonic float<->uint encoding for LDS atomicMin on floats
__device__ __forceinline__ uint_t fenc(float f) {
    uint_t u = __float_as_uint(f);
    return (u & 0x80000000u) ? ~u : (u | 0x80000000u);
}
__device__ __forceinline__ float fdec(uint_t k) {
    uint_t u = (k & 0x80000000u) ? (k ^ 0x80000000u) : ~k;
    return __uint_as_float(u);
}

typedef __attribute__((ext_vector_type(8))) short bf16x8;
typedef __attribute__((ext_vector_type(8))) unsigned short ushort8;
typedef __attribute__((ext_vector_type(4))) float f32x4;

__device__ __forceinline__ int swz(int r) { return (r & 3) ^ ((r >> 2) & 3); }

// ---------- prep2: ee (exact, same order as before) + Eh bf16 + zero loss --
__global__ void prep2_kernel(const float* __restrict__ emb, float* __restrict__ ee,
                             ushort_t* __restrict__ Eh, float* __restrict__ out_loss) {
    const int c = blockIdx.x, t = threadIdx.x;
    if (c == 0 && t == 0) out_loss[0] = 0.f;
    const float* e = emb + (size_t)c * DDIM;
    float s = 0.f;
    for (int i = t; i < DDIM; i += 256) { float v = e[i]; s += v * v; }
    for (int off = 32; off; off >>= 1) s += __shfl_down(s, off);
    __shared__ float red[4];
    if ((t & 63) == 0) red[t >> 6] = s;
    __syncthreads();
    if (t == 0) ee[c] = red[0] + red[1] + red[2] + red[3];
    if (t < 192) {
        const float4 v = ((const float4*)e)[t];
        ushort4 h;
        h.x = f2bf(v.x); h.y = f2bf(v.y); h.z = f2bf(v.z); h.w = f2bf(v.w);
        ((ushort4*)(Eh + (size_t)c * DDIM))[t] = h;
    }
}

// ------- fused3: round-0 GEMM geometry, 2 col-blocks, in-kernel A convert --
// Grid 512 = 256 rowblocks x 2 colblocks (1024 codes each, 2 chunks of 512).
// 256 threads / 4 waves, wave tile 64x128 (384 B/MFMA). 2 blocks/CU resident.
#define R      64
#define CCH    512
#define NCH    2            // 1024 codes per block / 512
#define KST    24           // 768/32
#define CAP    16
#define B_OFF    4096
#define RMIN_OFF 36864
#define RCNT_OFF 37120
#define SVAL_OFF 37376
#define SIDX_OFF 41472
#define SMEM_SZ  45568

__global__ __launch_bounds__(256, 2)
void fused3_kernel(const float* __restrict__ z, const ushort_t* __restrict__ Eh,
                   const float* __restrict__ ee, float* __restrict__ bmin,
                   float2* __restrict__ slots) {
    __shared__ __align__(16) char smem[SMEM_SZ];
    uint_t* rowminU = (uint_t*)(smem + RMIN_OFF);
    int*    rcnt    = (int*)(smem + RCNT_OFF);
    float (*sval)[CAP] = (float(*)[CAP])(smem + SVAL_OFF);
    int   (*sidx)[CAP] = (int(*)[CAP])(smem + SIDX_OFF);

    const int t = threadIdx.x;
    const int w = t >> 6, l = t & 63;
    // XCD-coherent decode: partner (cb=0/1) blocks differ by 8 -> same XCD
    const int idx = blockIdx.x;
    const int cb = (idx >> 3) & 1;
    const int rb = (idx & 7) | ((idx >> 4) << 3);
    const int row0 = rb * R;
    const int codebase = cb * (NCH * CCH);

    if (t < 64) { rowminU[t] = 0xFFFFFFFFu; rcnt[t] = 0; }

    // ---- A conversion mapping: thread -> (row, 8-elem K-sub-slot)
    const int arow = t >> 2, acs = t & 3;
    const float* zA = z + (size_t)(row0 + arow) * DDIM + acs * 8;
    char* aw = smem + (arow << 6) + ((acs ^ swz(arow)) << 4);

    // ---- B staging: LDS dest linear, global source pre-swizzled
    const int sri = l >> 2, slot = l & 3;
    const int swzs = swz(sri);
    const int brow = w * 128 + sri;
    const uint_t lB = B_OFF + (uint_t)(w * 8192);

    // ---- fragment LDS byte offsets
    const int g = l >> 4, lr = l & 15;
    int aoff[4], boff[8];
    #pragma unroll
    for (int mi = 0; mi < 4; ++mi) {
        const int r = mi * 16 + lr;
        aoff[mi] = (r << 6) + ((g ^ swz(r)) << 4);
    }
    #pragma unroll
    for (int ni = 0; ni < 8; ++ni) {
        const int rb2 = w * 128 + ni * 16 + lr;
        boff[ni] = B_OFF + (rb2 << 6) + ((g ^ swz(rb2)) << 4);
    }

    f32x4 acc[4][8];
    for (int c = 0; c < NCH; ++c) {
        const int c0 = codebase + c * CCH;
        #pragma unroll
        for (int mi = 0; mi < 4; ++mi)
            #pragma unroll
            for (int ni = 0; ni < 8; ++ni) acc[mi][ni] = (f32x4){0.f, 0.f, 0.f, 0.f};

        const ushort_t* gB = Eh + (size_t)(c0 + brow) * DDIM + ((slot ^ swzs) << 3);

        for (int s = 0; s < KST; ++s) {
            __syncthreads();                    // prior tile reads done
            #pragma unroll
            for (int q = 0; q < 8; ++q)
                __builtin_amdgcn_global_load_lds(
                    (const __attribute__((address_space(1))) void*)(gB + q * (16 * DDIM)),
                    (__attribute__((address_space(3))) void*)(smem + lB + q * 1024),
                    16, 0, 0);
            {   // A: f32 -> bf16 reg-staged convert into swizzled 4KB tile
                const float4 v0 = *(const float4*)(zA + 32 * s);
                const float4 v1 = *(const float4*)(zA + 32 * s + 4);
                ushort8 h;
                h[0] = f2bf(v0.x); h[1] = f2bf(v0.y); h[2] = f2bf(v0.z); h[3] = f2bf(v0.w);
                h[4] = f2bf(v1.x); h[5] = f2bf(v1.y); h[6] = f2bf(v1.z); h[7] = f2bf(v1.w);
                *(ushort8*)aw = h;
            }
            gB += 32;
            __syncthreads();                    // drains vmcnt + lgkm: tiles ready

            bf16x8 af[4], bfr[8];
            #pragma unroll
            for (int mi = 0; mi < 4; ++mi) af[mi] = *(const bf16x8*)(smem + aoff[mi]);
            #pragma unroll
            for (int ni = 0; ni < 8; ++ni) bfr[ni] = *(const bf16x8*)(smem + boff[ni]);
            #pragma unroll
            for (int mi = 0; mi < 4; ++mi)
                #pragma unroll
                for (int ni = 0; ni < 8; ++ni)
                    acc[mi][ni] = __builtin_amdgcn_mfma_f32_16x16x32_bf16(
                        af[mi], bfr[ni], acc[mi][ni], 0, 0, 0);
        }

        // ---- chunk epilogue: d~ = ee - 2*dot~, running row-min + candidates
        float ecv[8];
        #pragma unroll
        for (int ni = 0; ni < 8; ++ni) ecv[ni] = ee[c0 + w * 128 + ni * 16 + lr];
        #pragma unroll
        for (int mi = 0; mi < 4; ++mi)
            #pragma unroll
            for (int ni = 0; ni < 8; ++ni)
                #pragma unroll
                for (int r = 0; r < 4; ++r)
                    acc[mi][ni][r] = ecv[ni] - 2.0f * acc[mi][ni][r];

        #pragma unroll
        for (int mi = 0; mi < 4; ++mi)
            #pragma unroll
            for (int r = 0; r < 4; ++r) {
                float v = acc[mi][0][r];
                #pragma unroll
                for (int ni = 1; ni < 8; ++ni) v = fminf(v, acc[mi][ni][r]);
                v = fminf(v, __shfl_xor(v, 1));
                v = fminf(v, __shfl_xor(v, 2));
                v = fminf(v, __shfl_xor(v, 4));
                v = fminf(v, __shfl_xor(v, 8));
                if (lr == 0) atomicMin(&rowminU[mi * 16 + g * 4 + r], fenc(v));
            }
        __syncthreads();
        #pragma unroll
        for (int mi = 0; mi < 4; ++mi)
            #pragma unroll
            for (int r = 0; r < 4; ++r) {
                const int lrow = mi * 16 + g * 4 + r;
                const float lim = fdec(rowminU[lrow]) + MARGIN;   // running min
                #pragma unroll
                for (int ni = 0; ni < 8; ++ni) {
                    const float vv = acc[mi][ni][r];
                    if (vv <= lim) {
                        const int p = atomicAdd(&rcnt[lrow], 1);
                        if (p < CAP) {
                            sval[lrow][p] = vv;
                            sidx[lrow][p] = c0 + w * 128 + ni * 16 + lr;
                        }
                    }
                }
            }
        // next chunk's first __syncthreads orders these LDS ops vs restaging
    }
    __syncthreads();   // all appends visible

    // ---- write block results: bmin + 16 slots/row
    if (t < 64) bmin[(size_t)cb * NROWS + row0 + t] = fdec(rowminU[t]);
    {
        const int rr = t >> 2, qp = t & 3;
        const int n = rcnt[rr] < CAP ? rcnt[rr] : CAP;
        const int s0 = qp * 4;
        float v0 = (s0 + 0 < n) ? sval[rr][s0 + 0] : FLT_MAX;
        float v1 = (s0 + 1 < n) ? sval[rr][s0 + 1] : FLT_MAX;
        float v2 = (s0 + 2 < n) ? sval[rr][s0 + 2] : FLT_MAX;
        float v3 = (s0 + 3 < n) ? sval[rr][s0 + 3] : FLT_MAX;
        int i0 = (s0 + 0 < n) ? sidx[rr][s0 + 0] : 0x7fffffff;
        int i1 = (s0 + 1 < n) ? sidx[rr][s0 + 1] : 0x7fffffff;
        int i2 = (s0 + 2 < n) ? sidx[rr][s0 + 2] : 0x7fffffff;
        int i3 = (s0 + 3 < n) ? sidx[rr][s0 + 3] : 0x7fffffff;
        float4* dst = (float4*)(slots + ((size_t)cb * NROWS + row0 + rr) * CAP) + qp * 2;
        dst[0] = make_float4(v0, __int_as_float(i0), v1, __int_as_float(i1));
        dst[1] = make_float4(v2, __int_as_float(i2), v3, __int_as_float(i3));
    }
}

// -- combine2: min over 2 blocks + EXACT fp32 re-check + gather + loss ------
__global__ __launch_bounds__(256)
void combine2_kernel(const float* __restrict__ bmin, const float2* __restrict__ slots,
                     const float* __restrict__ ee, const float* __restrict__ z,
                     const float* __restrict__ emb, float* __restrict__ ids_f32,
                     float* __restrict__ out0, float* __restrict__ out_loss) {
    const int t = threadIdx.x;
    const int w = t >> 6;
    const int row = blockIdx.x * 4 + w;
    const int l = t & 63;

    float v = (l < 2) ? bmin[(size_t)l * NROWS + row] : FLT_MAX;
    v = fminf(v, __shfl_xor(v, 1));
    const float T = __shfl(v, 0) + MARGIN;

    // 32 slots per row (2 blocks x 16) in lanes 0..31
    float2 a = make_float2(FLT_MAX, __int_as_float(0x7fffffff));
    if (l < 32) a = slots[((size_t)(l >> 4) * NROWS + row) * CAP + (l & 15)];
    unsigned long long m = __ballot(a.x <= T);

    const float* zr = z + (size_t)row * DDIM;

    // exact zz, bit-identical reduction order to zz_kernel
    float szz = 0.f;
    #pragma unroll
    for (int k = 0; k < 12; ++k) { const float vz = zr[l + 64 * k]; szz += vz * vz; }
    for (int off = 32; off; off >>= 1) szz += __shfl_down(szz, off);
    const float zzr = __shfl(szz, 0);

    float bestd = FLT_MAX; int besti = 0x7fffffff;
    while (m) {
        const int j = __ffsll(m) - 1; m &= m - 1;
        const int cand = __float_as_int(__shfl(a.y, j));
        const float* er = emb + (size_t)cand * DDIM;
        float p = 0.f;
        #pragma unroll
        for (int k = 0; k < 12; ++k) p += zr[l + 64 * k] * er[l + 64 * k];
        for (int off = 32; off; off >>= 1) p += __shfl_down(p, off);
        if (l == 0) {
            const float t1 = zzr + ee[cand];     // fp32 round (ref order)
            const float d  = t1 - 2.0f * p;      // fp32 round
            if (d < bestd || (d == bestd && cand < besti)) { bestd = d; besti = cand; }
        }
    }
    const int bi = __shfl(besti, 0);
    if (l == 0) ids_f32[row] = (float)bi;

    // fused gather + straight-through + loss partial
    const float4* zr4 = (const float4*)zr;
    const float4* er4 = (const float4*)(emb + (size_t)bi * DDIM);
    float4* o4 = (float4*)(out0 + (size_t)row * DDIM);
    float s = 0.f;
    #pragma unroll
    for (int j = 0; j < 3; ++j) {
        const int i4 = l + 64 * j;
        const float4 zv = zr4[i4];
        const float4 ev = er4[i4];
        float4 o;
        o.x = zv.x + (ev.x - zv.x); o.y = zv.y + (ev.y - zv.y);
        o.z = zv.z + (ev.z - zv.z); o.w = zv.w + (ev.w - zv.w);
        o4[i4] = o;
        const float dx = zv.x - ev.x, dy = zv.y - ev.y;
        const float dz = zv.z - ev.z, dw = zv.w - ev.w;
        s += dx * dx + dy * dy + dz * dz + dw * dw;
    }
    for (int off = 32; off; off >>= 1) s += __shfl_down(s, off);
    __shared__ float lred[4];
    if (l == 0) lred[w] = s;
    __syncthreads();
    if (t == 0) {
        const float tot = lred[0] + lred[1] + lred[2] + lred[3];
        atomicAdd(out_loss, tot * (0.25f / (float)((size_t)NROWS * DDIM)));
    }
}

// ================= Fallback (round-3 exact fp32 path, proven) ==============
__global__ void ee_kernel(const float* __restrict__ emb, float* __restrict__ ee) {
    int c = blockIdx.x;
    const float* e = emb + (size_t)c * DDIM;
    int t = threadIdx.x;
    float s = 0.f;
    for (int i = t; i < DDIM; i += 256) { float v = e[i]; s += v * v; }
    for (int off = 32; off; off >>= 1) s += __shfl_down(s, off);
    __shared__ float red[4];
    if ((t & 63) == 0) red[t >> 6] = s;
    __syncthreads();
    if (t == 0) ee[c] = red[0] + red[1] + red[2] + red[3];
}

__global__ void zz_kernel(const float* __restrict__ z, float* __restrict__ zz) {
    const int t = threadIdx.x;
    const int row = blockIdx.x * 4 + (t >> 6);
    const int lane = t & 63;
    const float* zr = z + (size_t)row * DDIM;
    float s = 0.f;
    for (int i = lane; i < DDIM; i += 64) { float v = zr[i]; s += v * v; }
    for (int off = 32; off; off >>= 1) s += __shfl_down(s, off);
    if (lane == 0) zz[row] = s;
}

#define BM 32
#define BN 128
#define BKS 32
#define SPLITC 2
#define CODES_PER_BLOCK (KCODES / SPLITC)
#define NCHUNK (CODES_PER_BLOCK / BN)
#define NSTAGE (DDIM / BKS)
#define APADR 33
#define BPADC 132

__global__ __launch_bounds__(256)
void argmin_kernel(const float* __restrict__ z, const float* __restrict__ emb,
                   const float* __restrict__ ee, const float* __restrict__ zz,
                   float* __restrict__ pval, int* __restrict__ pidx) {
    __shared__ float Af[BKS][APADR];
    __shared__ float Bf[BKS][BPADC];
    __shared__ float cval[BM][33];
    __shared__ int   cidx[BM][33];
    __shared__ float zzs[BM];
    const int t = threadIdx.x;
    const int part = blockIdx.x & (SPLITC - 1);
    const int rb = blockIdx.x >> 1;
    const int row0 = rb * BM;
    const int cbase = part * CODES_PER_BLOCK;
    const int tx = t & 31, ty = t >> 5;
    const int sr = t >> 3;
    const int sk = 4 * (t & 7);
    if (t < BM) zzs[t] = zz[row0 + t];
    float bv[4]; int bi[4];
    #pragma unroll
    for (int i = 0; i < 4; ++i) { bv[i] = FLT_MAX; bi[i] = 0x7fffffff; }
    const float* zt = z + (size_t)(row0 + sr) * DDIM;
    for (int chunk = 0; chunk < NCHUNK; ++chunk) {
        const int c0 = cbase + chunk * BN;
        const float* ebase = emb + (size_t)(c0 + sr) * DDIM;
        float acc[4][4];
        #pragma unroll
        for (int i = 0; i < 4; ++i)
            #pragma unroll
            for (int j = 0; j < 4; ++j) acc[i][j] = 0.f;
        float4 pa = *(const float4*)&zt[sk];
        float4 pb[4];
        #pragma unroll
        for (int m = 0; m < 4; ++m) pb[m] = *(const float4*)&ebase[(size_t)(32 * m) * DDIM + sk];
        for (int s = 0; s < NSTAGE; ++s) {
            __syncthreads();
            Af[sk + 0][sr] = pa.x; Af[sk + 1][sr] = pa.y;
            Af[sk + 2][sr] = pa.z; Af[sk + 3][sr] = pa.w;
            #pragma unroll
            for (int m = 0; m < 4; ++m) {
                Bf[sk + 0][sr + 32 * m] = pb[m].x;
                Bf[sk + 1][sr + 32 * m] = pb[m].y;
                Bf[sk + 2][sr + 32 * m] = pb[m].z;
                Bf[sk + 3][sr + 32 * m] = pb[m].w;
            }
            __syncthreads();
            if (s + 1 < NSTAGE) {
                const int k1 = (s + 1) * BKS + sk;
                pa = *(const float4*)&zt[k1];
                #pragma unroll
                for (int m = 0; m < 4; ++m)
                    pb[m] = *(const float4*)&ebase[(size_t)(32 * m) * DDIM + k1];
            }
            #pragma unroll
            for (int kk = 0; kk < BKS; ++kk) {
                const float4 a4 = *(const float4*)&Af[kk][4 * ty];
                const float4 b4 = *(const float4*)&Bf[kk][4 * tx];
                const float aa[4] = {a4.x, a4.y, a4.z, a4.w};
                const float bb[4] = {b4.x, b4.y, b4.z, b4.w};
                #pragma unroll
                for (int i = 0; i < 4; ++i)
                    #pragma unroll
                    for (int j = 0; j < 4; ++j) acc[i][j] += aa[i] * bb[j];
            }
        }
        const float4 e4 = *(const float4*)&ee[c0 + 4 * tx];
        const float eev[4] = {e4.x, e4.y, e4.z, e4.w};
        #pragma unroll
        for (int i = 0; i < 4; ++i) {
            const float zzr = zzs[4 * ty + i];
            #pragma unroll
            for (int j = 0; j < 4; ++j) {
                const int code = c0 + 4 * tx + j;
                const float t1 = zzr + eev[j];
                const float d  = t1 - 2.0f * acc[i][j];
                if (d < bv[i] || (d == bv[i] && code < bi[i])) { bv[i] = d; bi[i] = code; }
            }
        }
    }
    __syncthreads();
    #pragma unroll
    for (int i = 0; i < 4; ++i) { cval[4 * ty + i][tx] = bv[i]; cidx[4 * ty + i][tx] = bi[i]; }
    __syncthreads();
    if (t < BM) {
        float v = FLT_MAX; int id = 0x7fffffff;
        #pragma unroll
        for (int x = 0; x < 32; ++x) {
            const float cv = cval[t][x]; const int ci = cidx[t][x];
            if (cv < v || (cv == v && ci < id)) { v = cv; id = ci; }
        }
        pval[part * NROWS + row0 + t] = v;
        pidx[part * NROWS + row0 + t] = id;
    }
}

__global__ void combine_kernel(const float* __restrict__ pval, const int* __restrict__ pidx,
                               float* __restrict__ ids_f32) {
    const int r = blockIdx.x * 256 + threadIdx.x;
    float v = pval[r];           int id = pidx[r];
    const float v1 = pval[NROWS + r]; const int i1 = pidx[NROWS + r];
    if (v1 < v || (v1 == v && i1 < id)) { v = v1; id = i1; }
    ids_f32[r] = (float)id;
}

__global__ __launch_bounds__(256)
void gather_kernel(const float* __restrict__ z, const float* __restrict__ emb,
                   const float* __restrict__ ids_f32, float* __restrict__ out0,
                   float* __restrict__ part) {
    const int b = blockIdx.x;
    const int t = threadIdx.x;
    const int rl = t >> 4, c = t & 15;
    __shared__ int ids[16];
    if (t < 16) ids[t] = (int)ids_f32[b * 16 + t];
    __syncthreads();
    const int row = b * 16 + rl;
    const float4* zr = (const float4*)(z + (size_t)row * DDIM);
    float4* orow = (float4*)(out0 + (size_t)row * DDIM);
    const float4* er = (const float4*)(emb + (size_t)ids[rl] * DDIM);
    float s = 0.f;
    #pragma unroll
    for (int j = 0; j < 12; ++j) {
        const int i4 = c + 16 * j;
        const float4 zv = zr[i4];
        const float4 ev = er[i4];
        float4 o;
        o.x = zv.x + (ev.x - zv.x); o.y = zv.y + (ev.y - zv.y);
        o.z = zv.z + (ev.z - zv.z); o.w = zv.w + (ev.w - zv.w);
        orow[i4] = o;
        float dx = zv.x - ev.x, dy = zv.y - ev.y, dz = zv.z - ev.z, dw = zv.w - ev.w;
        s += dx * dx + dy * dy + dz * dz + dw * dw;
    }
    for (int off = 32; off; off >>= 1) s += __shfl_down(s, off);
    __shared__ float red[4];
    if ((t & 63) == 0) red[t >> 6] = s;
    __syncthreads();
    if (t == 0) part[b] = red[0] + red[1] + red[2] + red[3];
}

__global__ void loss_kernel(const float* __restrict__ part, float* __restrict__ out_loss) {
    const int t = threadIdx.x;
    double s = 0.0;
    for (int i = t; i < 1024; i += 256) s += (double)part[i];
    for (int off = 32; off; off >>= 1) s += __shfl_down(s, off);
    __shared__ double red[4];
    if ((t & 63) == 0) red[t >> 6] = s;
    __syncthreads();
    if (t == 0) {
        const double total = red[0] + red[1] + red[2] + red[3];
        out_loss[0] = (float)(0.25 * (total / (double)((size_t)NROWS * DDIM)));
    }
}

// ================= launch ==================================================
#define EE_OFF   0
#define ZZ_OFF   8192
#define EH_OFF   73728
#define BMIN_OFF (EH_OFF + (size_t)KCODES * DDIM * 2)       // +3145728
#define SLOT_OFF (BMIN_OFF + (size_t)2 * NROWS * 4)         // +131072
#define WS_NEED  (SLOT_OFF + (size_t)2 * NROWS * CAP * 8)   // ~7.5 MB
#define PART_OFF 73728                                      // fallback (exclusive)
#define PV_OFF   81920

extern "C" void kernel_launch(void* const* d_in, const int* in_sizes, int n_in,
                              void* d_out, int out_size, void* d_ws, size_t ws_size,
                              hipStream_t stream) {
    const float* z   = (const float*)d_in[0];
    const float* emb = (const float*)d_in[1];

    float* out0     = (float*)d_out;
    float* out_ids  = out0 + (size_t)NROWS * DDIM;
    float* out_loss = out_ids + NROWS;

    char* ws = (char*)d_ws;
    float* ee   = (float*)(ws + EE_OFF);
    float* zzws = (float*)(ws + ZZ_OFF);

    if (ws_size >= WS_NEED) {
        ushort_t* Eh   = (ushort_t*)(ws + EH_OFF);
        float*    bmin = (float*)(ws + BMIN_OFF);
        float2*   slot = (float2*)(ws + SLOT_OFF);
        prep2_kernel<<<KCODES, 256, 0, stream>>>(emb, ee, Eh, out_loss);
        fused3_kernel<<<512, 256, 0, stream>>>(z, Eh, ee, bmin, slot);
        combine2_kernel<<<NROWS / 4, 256, 0, stream>>>(bmin, slot, ee, z, emb,
                                                       out_ids, out0, out_loss);
    } else {
        float* part = (float*)(ws + PART_OFF);
        float* pval = (float*)(ws + PV_OFF);
        int*   pidx = (int*)(ws + PV_OFF + 131072);
        ee_kernel<<<KCODES, 256, 0, stream>>>(emb, ee);
        zz_kernel<<<NROWS / 4, 256, 0, stream>>>(z, zzws);
        argmin_kernel<<<(NROWS / BM) * SPLITC, 256, 0, stream>>>(z, emb, ee, zzws, pval, pidx);
        combine_kernel<<<NROWS / 256, 256, 0, stream>>>(pval, pidx, out_ids);
        gather_kernel<<<NROWS / 16, 256, 0, stream>>>(z, emb, out_ids, out0, part);
        loss_kernel<<<1, 256, 0, stream>>>(part, out_loss);
    }
}

// Round 4
// 241.995 us; speedup vs baseline: 1.1490x; 1.0037x over previous
//
#include <hip/hip_runtime.h>
#include <float.h>

typedef unsigned short ushort_t;
typedef unsigned int uint_t;

// Problem constants
#define NROWS 16384   // 8*2048
#define DDIM  768
#define KCODES 2048
#define NCB2   8      // code blocks (2048/256)
#define MARGIN 8e-4f

// bf16 helpers (RNE)
__device__ __forceinline__ ushort_t f2bf(float x) {
    uint_t u = __float_as_uint(x);
    uint_t r = (u + 0x7fffu + ((u >> 16) & 1u)) >> 16;
    return (ushort_t)r;
}

// monotonic float<->uint encoding for LDS atomicMin on floats
__device__ __forceinline__ uint_t fenc(float f) {
    uint_t u = __float_as_uint(f);
    return (u & 0x80000000u) ? ~u : (u | 0x80000000u);
}
__device__ __forceinline__ float fdec(uint_t k) {
    uint_t u = (k & 0x80000000u) ? (k ^ 0x80000000u) : ~k;
    return __uint_as_float(u);
}

// ---------- prep: ee + zz + bf16 converts + zero loss (round-0 proven) -----
__global__ void prep_kernel(const float* __restrict__ z, const float* __restrict__ emb,
                            float* __restrict__ ee, float* __restrict__ zz,
                            ushort_t* __restrict__ Zh, ushort_t* __restrict__ Eh,
                            float* __restrict__ out_loss) {
    const int b = blockIdx.x, t = threadIdx.x;
    if (b == 0 && t == 0) out_loss[0] = 0.f;
    if (b < KCODES) {
        const int c = b;
        const float* e = emb + (size_t)c * DDIM;
        float s = 0.f;
        for (int i = t; i < DDIM; i += 256) { float v = e[i]; s += v * v; }
        for (int off = 32; off; off >>= 1) s += __shfl_down(s, off);
        __shared__ float red[4];
        if ((t & 63) == 0) red[t >> 6] = s;
        __syncthreads();
        if (t == 0) ee[c] = red[0] + red[1] + red[2] + red[3];
        if (t < 192) {
            const float4 v = ((const float4*)e)[t];
            ushort4 h;
            h.x = f2bf(v.x); h.y = f2bf(v.y); h.z = f2bf(v.z); h.w = f2bf(v.w);
            ((ushort4*)(Eh + (size_t)c * DDIM))[t] = h;
        }
    } else {
        const int rb = b - KCODES;
        const int row = rb * 4 + (t >> 6);
        const int lane = t & 63;
        const float* zr = z + (size_t)row * DDIM;
        float s = 0.f;
        for (int i = lane; i < DDIM; i += 64) { float v = zr[i]; s += v * v; }
        for (int off = 32; off; off >>= 1) s += __shfl_down(s, off);
        if (lane == 0) zz[row] = s;
        const float4* zr4 = (const float4*)zr;
        ushort4* dh = (ushort4*)(Zh + (size_t)row * DDIM);
        #pragma unroll
        for (int j = 0; j < 3; ++j) {
            const int i4 = lane + 64 * j;
            const float4 v = zr4[i4];
            ushort4 h;
            h.x = f2bf(v.x); h.y = f2bf(v.y); h.z = f2bf(v.z); h.w = f2bf(v.w);
            dh[i4] = h;
        }
    }
}

// ---------------- Phase 1: ring-3 counted-vmcnt MFMA GEMM 128x256 ----------
typedef __attribute__((ext_vector_type(8))) short bf16x8;
typedef __attribute__((ext_vector_type(4))) float f32x4;

__device__ __forceinline__ int swz(int r) { return (r & 3) ^ ((r >> 2) & 3); }

#define RINGB 24576
#define CAPS  8

__global__ __launch_bounds__(256, 2)
void mfma_ring_kernel(const ushort_t* __restrict__ Ab, const ushort_t* __restrict__ Bb,
                      const float* __restrict__ ee, float* __restrict__ bmin,
                      float2* __restrict__ slots) {
    // 3 ring buffers of one K-tile each: A 128x64B @ +0, B 256x64B @ +8192
    __shared__ __align__(16) char smem[3 * RINGB];
    // epilogue aliases (used only after the K-loop)
    uint_t* rowminU = (uint_t*)smem;                 // 128 * 4
    int*    rcnt    = (int*)(smem + 512);            // 128 * 4
    float (*sval)[CAPS] = (float(*)[CAPS])(smem + 1024);  // 4KB
    int   (*sidx)[CAPS] = (int(*)[CAPS])(smem + 5120);    // 4KB

    const int t = threadIdx.x;
    const int w = t >> 6, l = t & 63;
    const int bx = blockIdx.x & 127;   // 128 row-blocks
    const int by = blockIdx.x >> 7;    // 8 col-blocks
    const int row0 = bx << 7;          // *128
    const int col0 = by << 8;          // *256

    f32x4 acc[4][8];
    #pragma unroll
    for (int i = 0; i < 4; ++i)
        #pragma unroll
        for (int j = 0; j < 8; ++j) acc[i][j] = (f32x4){0.f, 0.f, 0.f, 0.f};

    // staging pointers (round-0 proven maps); k advances via global ptr only
    const int sri = l >> 2, slot = l & 3;
    const ushort_t* gA[2]; uint_t lA[2];
    #pragma unroll
    for (int q = 0; q < 2; ++q) {
        const int r0 = ((w << 1) + q) << 4;
        const int ra = r0 + sri;
        const int c  = slot ^ swz(ra);
        gA[q] = Ab + (size_t)(row0 + ra) * DDIM + (c << 3);
        lA[q] = r0 << 6;
    }
    const ushort_t* gB[4]; uint_t lB[4];
    #pragma unroll
    for (int q = 0; q < 4; ++q) {
        const int r0 = ((w << 2) + q) << 4;
        const int ra = r0 + sri;
        const int c  = slot ^ swz(ra);
        gB[q] = Bb + (size_t)(col0 + ra) * DDIM + (c << 3);
        lB[q] = 8192 + (r0 << 6);
    }

    // fragment LDS byte offsets (ring-relative, loop-invariant)
    const int rha = (w & 1) << 6;    // row half (0/64)
    const int chb = (w >> 1) << 7;   // col half (0/128)
    int aoff[4], boff[8];
    #pragma unroll
    for (int mi = 0; mi < 4; ++mi) {
        const int r = rha + (mi << 4) + (l & 15);
        const int sw = (l >> 4) ^ swz(r);
        aoff[mi] = (r << 6) + (sw << 4);
    }
    #pragma unroll
    for (int ni = 0; ni < 8; ++ni) {
        const int r = chb + (ni << 4) + (l & 15);
        const int sw = (l >> 4) ^ swz(r);
        boff[ni] = 8192 + (r << 6) + (sw << 4);
    }

#define STAGE(base_) do {                                                     \
        _Pragma("unroll")                                                     \
        for (int q = 0; q < 2; ++q) {                                         \
            __builtin_amdgcn_global_load_lds(                                 \
                (const __attribute__((address_space(1))) void*)gA[q],         \
                (__attribute__((address_space(3))) void*)(smem + (base_) + lA[q]), \
                16, 0, 0);                                                    \
            gA[q] += 32;                                                      \
        }                                                                     \
        _Pragma("unroll")                                                     \
        for (int q = 0; q < 4; ++q) {                                         \
            __builtin_amdgcn_global_load_lds(                                 \
                (const __attribute__((address_space(1))) void*)gB[q],         \
                (__attribute__((address_space(3))) void*)(smem + (base_) + lB[q]), \
                16, 0, 0);                                                    \
            gB[q] += 32;                                                      \
        }                                                                     \
    } while (0)

    // prologue: tiles 0,1 into rings 0,1; full drain once
    STAGE(0);
    STAGE(RINGB);
    __syncthreads();

    int cur = 0, stg = 2;                      // ring of tile kt / tile kt+2
    for (int kt = 0; kt < 24; ++kt) {          // k-order 0..767, frozen
        if (kt < 22) STAGE((uint_t)stg * RINGB);

        const char* cb_ = smem + (uint_t)cur * RINGB;
        bf16x8 af[4], bfr[8];
        #pragma unroll
        for (int mi = 0; mi < 4; ++mi) af[mi] = *(const bf16x8*)(cb_ + aoff[mi]);
        #pragma unroll
        for (int ni = 0; ni < 8; ++ni) bfr[ni] = *(const bf16x8*)(cb_ + boff[ni]);

        __builtin_amdgcn_s_setprio(1);
        #pragma unroll
        for (int mi = 0; mi < 4; ++mi)
            #pragma unroll
            for (int ni = 0; ni < 8; ++ni)
                acc[mi][ni] = __builtin_amdgcn_mfma_f32_16x16x32_bf16(
                    af[mi], bfr[ni], acc[mi][ni], 0, 0, 0);
        __builtin_amdgcn_s_setprio(0);

        // gate: tile kt+1 loads complete; tile kt+2's 6 stay in flight
        if (kt < 22) asm volatile("s_waitcnt vmcnt(6)" ::: "memory");
        else         asm volatile("s_waitcnt vmcnt(0)" ::: "memory");
        __builtin_amdgcn_sched_barrier(0);
        __builtin_amdgcn_s_barrier();
        __builtin_amdgcn_sched_barrier(0);

        cur = (cur == 2) ? 0 : cur + 1;
        stg = (stg == 2) ? 0 : stg + 1;
    }
#undef STAGE

    __syncthreads();   // tile reads done before epilogue aliases smem

    // ---- epilogue: d~ = ee - 2*dot~ (fp32, frozen ops), block-min + slots
    if (t < 128) { rowminU[t] = 0xFFFFFFFFu; rcnt[t] = 0; }
    __syncthreads();

    float ecv[8];
    #pragma unroll
    for (int ni = 0; ni < 8; ++ni) ecv[ni] = ee[col0 + chb + (ni << 4) + (l & 15)];
    #pragma unroll
    for (int mi = 0; mi < 4; ++mi)
        #pragma unroll
        for (int ni = 0; ni < 8; ++ni)
            #pragma unroll
            for (int r = 0; r < 4; ++r)
                acc[mi][ni][r] = ecv[ni] - 2.0f * acc[mi][ni][r];

    #pragma unroll
    for (int mi = 0; mi < 4; ++mi)
        #pragma unroll
        for (int r = 0; r < 4; ++r) {
            float v = acc[mi][0][r];
            #pragma unroll
            for (int ni = 1; ni < 8; ++ni) v = fminf(v, acc[mi][ni][r]);
            v = fminf(v, __shfl_xor(v, 1));
            v = fminf(v, __shfl_xor(v, 2));
            v = fminf(v, __shfl_xor(v, 4));
            v = fminf(v, __shfl_xor(v, 8));
            if ((l & 15) == 0)
                atomicMin(&rowminU[rha + (mi << 4) + ((l >> 4) << 2) + r], fenc(v));
        }
    __syncthreads();

    #pragma unroll
    for (int mi = 0; mi < 4; ++mi)
        #pragma unroll
        for (int r = 0; r < 4; ++r) {
            const int m = rha + (mi << 4) + ((l >> 4) << 2) + r;
            const float lim = fdec(rowminU[m]) + MARGIN;
            #pragma unroll
            for (int ni = 0; ni < 8; ++ni) {
                const float vv = acc[mi][ni][r];
                if (vv <= lim) {
                    const int p = atomicAdd(&rcnt[m], 1);
                    if (p < CAPS) {
                        sval[m][p] = vv;
                        sidx[m][p] = col0 + chb + (ni << 4) + (l & 15);
                    }
                }
            }
        }
    __syncthreads();

    if (t < 128) {
        const int row = row0 + t;
        bmin[(size_t)by * NROWS + row] = fdec(rowminU[t]);
        const int n = rcnt[t] < CAPS ? rcnt[t] : CAPS;
        float2 rec[8];
        #pragma unroll
        for (int s2 = 0; s2 < 8; ++s2)
            rec[s2] = (s2 < n) ? make_float2(sval[t][s2], __int_as_float(sidx[t][s2]))
                               : make_float2(FLT_MAX, __int_as_float(0x7fffffff));
        float4* dst = (float4*)(slots + ((size_t)by * NROWS + row) * 8);
        dst[0] = make_float4(rec[0].x, rec[0].y, rec[1].x, rec[1].y);
        dst[1] = make_float4(rec[2].x, rec[2].y, rec[3].x, rec[3].y);
        dst[2] = make_float4(rec[4].x, rec[4].y, rec[5].x, rec[5].y);
        dst[3] = make_float4(rec[6].x, rec[6].y, rec[7].x, rec[7].y);
    }
}

// -- Phase 2: combine + EXACT fp32 re-check (frozen) + gather + loss atomic -
__global__ __launch_bounds__(256)
void combine_select_gather(const float* __restrict__ bmin, const float2* __restrict__ slots,
                           const float* __restrict__ ee, const float* __restrict__ zz,
                           const float* __restrict__ z, const float* __restrict__ emb,
                           float* __restrict__ ids_f32, float* __restrict__ out0,
                           float* __restrict__ out_loss) {
    const int t = threadIdx.x;
    const int w = t >> 6;
    const int row = blockIdx.x * 4 + w;
    const int l = t & 63;

    float v = (l < NCB2) ? bmin[(size_t)l * NROWS + row] : FLT_MAX;
    v = fminf(v, __shfl_xor(v, 4));
    v = fminf(v, __shfl_xor(v, 2));
    v = fminf(v, __shfl_xor(v, 1));
    const float T = __shfl(v, 0) + MARGIN;

    // 64 slots per row (8 blocks x 8) -> exactly one float2 per lane
    const int blk = l >> 3;
    const int s0 = l & 7;
    const float2 a = slots[((size_t)blk * NROWS + row) * 8 + s0];

    unsigned long long m = __ballot(a.x <= T);

    const float* zr = z + (size_t)row * DDIM;
    int bi;
    if (__popcll(m) == 1) {
        // sole survivor is provably the exact argmin (margin >= bf16 bound)
        bi = __float_as_int(__shfl(a.y, __ffsll(m) - 1));
    } else {
        const float zzr = zz[row];
        float bestd = FLT_MAX; int besti = 0x7fffffff;
        while (m) {
            const int j = __ffsll(m) - 1; m &= m - 1;
            const int idx = __float_as_int(__shfl(a.y, j));
            const float* er = emb + (size_t)idx * DDIM;
            float p = 0.f;
            #pragma unroll
            for (int k = 0; k < 12; ++k) p += zr[l + 64 * k] * er[l + 64 * k];
            for (int off = 32; off; off >>= 1) p += __shfl_down(p, off);
            if (l == 0) {
                const float t1 = zzr + ee[idx];     // fp32 round (ref order)
                const float d  = t1 - 2.0f * p;     // fp32 round
                if (d < bestd || (d == bestd && idx < besti)) { bestd = d; besti = idx; }
            }
        }
        bi = __shfl(besti, 0);
    }
    if (l == 0) ids_f32[row] = (float)bi;

    // fused gather + straight-through + loss partial
    const float4* zr4 = (const float4*)zr;
    const float4* er4 = (const float4*)(emb + (size_t)bi * DDIM);
    float4* o4 = (float4*)(out0 + (size_t)row * DDIM);
    float s = 0.f;
    #pragma unroll
    for (int j = 0; j < 3; ++j) {
        const int i4 = l + 64 * j;
        const float4 zv = zr4[i4];
        const float4 ev = er4[i4];
        float4 o;
        o.x = zv.x + (ev.x - zv.x); o.y = zv.y + (ev.y - zv.y);
        o.z = zv.z + (ev.z - zv.z); o.w = zv.w + (ev.w - zv.w);
        o4[i4] = o;
        const float dx = zv.x - ev.x, dy = zv.y - ev.y;
        const float dz = zv.z - ev.z, dw = zv.w - ev.w;
        s += dx * dx + dy * dy + dz * dz + dw * dw;
    }
    for (int off = 32; off; off >>= 1) s += __shfl_down(s, off);
    __shared__ float lred[4];
    if (l == 0) lred[w] = s;
    __syncthreads();
    if (t == 0) {
        const float tot = lred[0] + lred[1] + lred[2] + lred[3];
        atomicAdd(out_loss, tot * (0.25f / (float)((size_t)NROWS * DDIM)));
    }
}

// ================= Fallback (round-3 exact fp32 path, proven) ==============
__global__ void ee_kernel(const float* __restrict__ emb, float* __restrict__ ee) {
    int c = blockIdx.x;
    const float* e = emb + (size_t)c * DDIM;
    int t = threadIdx.x;
    float s = 0.f;
    for (int i = t; i < DDIM; i += 256) { float v = e[i]; s += v * v; }
    for (int off = 32; off; off >>= 1) s += __shfl_down(s, off);
    __shared__ float red[4];
    if ((t & 63) == 0) red[t >> 6] = s;
    __syncthreads();
    if (t == 0) ee[c] = red[0] + red[1] + red[2] + red[3];
}

__global__ void zz_kernel(const float* __restrict__ z, float* __restrict__ zz) {
    const int t = threadIdx.x;
    const int row = blockIdx.x * 4 + (t >> 6);
    const int lane = t & 63;
    const float* zr = z + (size_t)row * DDIM;
    float s = 0.f;
    for (int i = lane; i < DDIM; i += 64) { float v = zr[i]; s += v * v; }
    for (int off = 32; off; off >>= 1) s += __shfl_down(s, off);
    if (lane == 0) zz[row] = s;
}

#define BM 32
#define BN 128
#define BKS 32
#define SPLITC 2
#define CODES_PER_BLOCK (KCODES / SPLITC)
#define NCHUNK (CODES_PER_BLOCK / BN)
#define NSTAGE (DDIM / BKS)
#define APADR 33
#define BPADC 132

__global__ __launch_bounds__(256)
void argmin_kernel(const float* __restrict__ z, const float* __restrict__ emb,
                   const float* __restrict__ ee, const float* __restrict__ zz,
                   float* __restrict__ pval, int* __restrict__ pidx) {
    __shared__ float Af[BKS][APADR];
    __shared__ float Bf[BKS][BPADC];
    __shared__ float cval[BM][33];
    __shared__ int   cidx[BM][33];
    __shared__ float zzs[BM];
    const int t = threadIdx.x;
    const int part = blockIdx.x & (SPLITC - 1);
    const int rb = blockIdx.x >> 1;
    const int row0 = rb * BM;
    const int cbase = part * CODES_PER_BLOCK;
    const int tx = t & 31, ty = t >> 5;
    const int sr = t >> 3;
    const int sk = 4 * (t & 7);
    if (t < BM) zzs[t] = zz[row0 + t];
    float bv[4]; int bi[4];
    #pragma unroll
    for (int i = 0; i < 4; ++i) { bv[i] = FLT_MAX; bi[i] = 0x7fffffff; }
    const float* zt = z + (size_t)(row0 + sr) * DDIM;
    for (int chunk = 0; chunk < NCHUNK; ++chunk) {
        const int c0 = cbase + chunk * BN;
        const float* ebase = emb + (size_t)(c0 + sr) * DDIM;
        float acc[4][4];
        #pragma unroll
        for (int i = 0; i < 4; ++i)
            #pragma unroll
            for (int j = 0; j < 4; ++j) acc[i][j] = 0.f;
        float4 pa = *(const float4*)&zt[sk];
        float4 pb[4];
        #pragma unroll
        for (int m = 0; m < 4; ++m) pb[m] = *(const float4*)&ebase[(size_t)(32 * m) * DDIM + sk];
        for (int s = 0; s < NSTAGE; ++s) {
            __syncthreads();
            Af[sk + 0][sr] = pa.x; Af[sk + 1][sr] = pa.y;
            Af[sk + 2][sr] = pa.z; Af[sk + 3][sr] = pa.w;
            #pragma unroll
            for (int m = 0; m < 4; ++m) {
                Bf[sk + 0][sr + 32 * m] = pb[m].x;
                Bf[sk + 1][sr + 32 * m] = pb[m].y;
                Bf[sk + 2][sr + 32 * m] = pb[m].z;
                Bf[sk + 3][sr + 32 * m] = pb[m].w;
            }
            __syncthreads();
            if (s + 1 < NSTAGE) {
                const int k1 = (s + 1) * BKS + sk;
                pa = *(const float4*)&zt[k1];
                #pragma unroll
                for (int m = 0; m < 4; ++m)
                    pb[m] = *(const float4*)&ebase[(size_t)(32 * m) * DDIM + k1];
            }
            #pragma unroll
            for (int kk = 0; kk < BKS; ++kk) {
                const float4 a4 = *(const float4*)&Af[kk][4 * ty];
                const float4 b4 = *(const float4*)&Bf[kk][4 * tx];
                const float aa[4] = {a4.x, a4.y, a4.z, a4.w};
                const float bb[4] = {b4.x, b4.y, b4.z, b4.w};
                #pragma unroll
                for (int i = 0; i < 4; ++i)
                    #pragma unroll
                    for (int j = 0; j < 4; ++j) acc[i][j] += aa[i] * bb[j];
            }
        }
        const float4 e4 = *(const float4*)&ee[c0 + 4 * tx];
        const float eev[4] = {e4.x, e4.y, e4.z, e4.w};
        #pragma unroll
        for (int i = 0; i < 4; ++i) {
            const float zzr = zzs[4 * ty + i];
            #pragma unroll
            for (int j = 0; j < 4; ++j) {
                const int code = c0 + 4 * tx + j;
                const float t1 = zzr + eev[j];
                const float d  = t1 - 2.0f * acc[i][j];
                if (d < bv[i] || (d == bv[i] && code < bi[i])) { bv[i] = d; bi[i] = code; }
            }
        }
    }
    __syncthreads();
    #pragma unroll
    for (int i = 0; i < 4; ++i) { cval[4 * ty + i][tx] = bv[i]; cidx[4 * ty + i][tx] = bi[i]; }
    __syncthreads();
    if (t < BM) {
        float v = FLT_MAX; int id = 0x7fffffff;
        #pragma unroll
        for (int x = 0; x < 32; ++x) {
            const float cv = cval[t][x]; const int ci = cidx[t][x];
            if (cv < v || (cv == v && ci < id)) { v = cv; id = ci; }
        }
        pval[part * NROWS + row0 + t] = v;
        pidx[part * NROWS + row0 + t] = id;
    }
}

__global__ void combine_kernel(const float* __restrict__ pval, const int* __restrict__ pidx,
                               float* __restrict__ ids_f32) {
    const int r = blockIdx.x * 256 + threadIdx.x;
    float v = pval[r];           int id = pidx[r];
    const float v1 = pval[NROWS + r]; const int i1 = pidx[NROWS + r];
    if (v1 < v || (v1 == v && i1 < id)) { v = v1; id = i1; }
    ids_f32[r] = (float)id;
}

__global__ __launch_bounds__(256)
void gather_kernel(const float* __restrict__ z, const float* __restrict__ emb,
                   const float* __restrict__ ids_f32, float* __restrict__ out0,
                   float* __restrict__ part) {
    const int b = blockIdx.x;
    const int t = threadIdx.x;
    const int rl = t >> 4, c = t & 15;
    __shared__ int ids[16];
    if (t < 16) ids[t] = (int)ids_f32[b * 16 + t];
    __syncthreads();
    const int row = b * 16 + rl;
    const float4* zr = (const float4*)(z + (size_t)row * DDIM);
    float4* orow = (float4*)(out0 + (size_t)row * DDIM);
    const float4* er = (const float4*)(emb + (size_t)ids[rl] * DDIM);
    float s = 0.f;
    #pragma unroll
    for (int j = 0; j < 12; ++j) {
        const int i4 = c + 16 * j;
        const float4 zv = zr[i4];
        const float4 ev = er[i4];
        float4 o;
        o.x = zv.x + (ev.x - zv.x); o.y = zv.y + (ev.y - zv.y);
        o.z = zv.z + (ev.z - zv.z); o.w = zv.w + (ev.w - zv.w);
        orow[i4] = o;
        float dx = zv.x - ev.x, dy = zv.y - ev.y, dz = zv.z - ev.z, dw = zv.w - ev.w;
        s += dx * dx + dy * dy + dz * dz + dw * dw;
    }
    for (int off = 32; off; off >>= 1) s += __shfl_down(s, off);
    __shared__ float red[4];
    if ((t & 63) == 0) red[t >> 6] = s;
    __syncthreads();
    if (t == 0) part[b] = red[0] + red[1] + red[2] + red[3];
}

__global__ void loss_kernel(const float* __restrict__ part, float* __restrict__ out_loss) {
    const int t = threadIdx.x;
    double s = 0.0;
    for (int i = t; i < 1024; i += 256) s += (double)part[i];
    for (int off = 32; off; off >>= 1) s += __shfl_down(s, off);
    __shared__ double red[4];
    if ((t & 63) == 0) red[t >> 6] = s;
    __syncthreads();
    if (t == 0) {
        const double total = red[0] + red[1] + red[2] + red[3];
        out_loss[0] = (float)(0.25 * (total / (double)((size_t)NROWS * DDIM)));
    }
}

// ================= launch ==================================================
#define EE_OFF   0
#define ZZ_OFF   8192
#define EH_OFF   73728
#define ZH_OFF   (EH_OFF + (size_t)KCODES * DDIM * 2)       // +3145728
#define BMIN_OFF (ZH_OFF + (size_t)NROWS * DDIM * 2)        // +25165824
#define SLOT_OFF (BMIN_OFF + (size_t)NCB2 * NROWS * 4)      // +524288
#define WS_NEED  (SLOT_OFF + (size_t)NCB2 * NROWS * 8 * 8)  // ~35.6 MB
#define PART_OFF 73728                                      // fallback (exclusive)
#define PV_OFF   81920

extern "C" void kernel_launch(void* const* d_in, const int* in_sizes, int n_in,
                              void* d_out, int out_size, void* d_ws, size_t ws_size,
                              hipStream_t stream) {
    const float* z   = (const float*)d_in[0];
    const float* emb = (const float*)d_in[1];

    float* out0     = (float*)d_out;
    float* out_ids  = out0 + (size_t)NROWS * DDIM;
    float* out_loss = out_ids + NROWS;

    char* ws = (char*)d_ws;
    float* ee   = (float*)(ws + EE_OFF);
    float* zzws = (float*)(ws + ZZ_OFF);

    if (ws_size >= WS_NEED) {
        ushort_t* Eh   = (ushort_t*)(ws + EH_OFF);
        ushort_t* Zh   = (ushort_t*)(ws + ZH_OFF);
        float*    bmin = (float*)(ws + BMIN_OFF);
        float2*   slot = (float2*)(ws + SLOT_OFF);
        prep_kernel<<<KCODES + NROWS / 4, 256, 0, stream>>>(z, emb, ee, zzws, Zh, Eh, out_loss);
        mfma_ring_kernel<<<(NROWS / 128) * NCB2, 256, 0, stream>>>(Zh, Eh, ee, bmin, slot);
        combine_select_gather<<<NROWS / 4, 256, 0, stream>>>(bmin, slot, ee, zzws, z, emb,
                                                             out_ids, out0, out_loss);
    } else {
        float* part = (float*)(ws + PART_OFF);
        float* pval = (float*)(ws + PV_OFF);
        int*   pidx = (int*)(ws + PV_OFF + 131072);
        ee_kernel<<<KCODES, 256, 0, stream>>>(emb, ee);
        zz_kernel<<<NROWS / 4, 256, 0, stream>>>(z, zzws);
        argmin_kernel<<<(NROWS / BM) * SPLITC, 256, 0, stream>>>(z, emb, ee, zzws, pval, pidx);
        combine_kernel<<<NROWS / 256, 256, 0, stream>>>(pval, pidx, out_ids);
        gather_kernel<<<NROWS / 16, 256, 0, stream>>>(z, emb, out_ids, out0, part);
        loss_kernel<<<1, 256, 0, stream>>>(part, out_loss);
    }
}

// Round 5
// 241.938 us; speedup vs baseline: 1.1493x; 1.0002x over previous
//
#include <hip/hip_runtime.h>
#include <float.h>

typedef unsigned short ushort_t;
typedef unsigned int uint_t;

// Problem constants
#define NROWS 16384   // 8*2048
#define DDIM  768
#define KCODES 2048
#define NCB2   8      // code blocks (2048/256)
#define MARGIN 8e-4f

// bf16 helpers (RNE)
__device__ __forceinline__ ushort_t f2bf(float x) {
    uint_t u = __float_as_uint(x);
    uint_t r = (u + 0x7fffu + ((u >> 16) & 1u)) >> 16;
    return (ushort_t)r;
}

// monotonic float<->uint encoding for LDS atomicMin on floats
__device__ __forceinline__ uint_t fenc(float f) {
    uint_t u = __float_as_uint(f);
    return (u & 0x80000000u) ? ~u : (u | 0x80000000u);
}
__device__ __forceinline__ float fdec(uint_t k) {
    uint_t u = (k & 0x80000000u) ? (k ^ 0x80000000u) : ~k;
    return __uint_as_float(u);
}

// ---------- prep: ee + zz + bf16 converts + zero loss (round-0 proven) -----
__global__ void prep_kernel(const float* __restrict__ z, const float* __restrict__ emb,
                            float* __restrict__ ee, float* __restrict__ zz,
                            ushort_t* __restrict__ Zh, ushort_t* __restrict__ Eh,
                            float* __restrict__ out_loss) {
    const int b = blockIdx.x, t = threadIdx.x;
    if (b == 0 && t == 0) out_loss[0] = 0.f;
    if (b < KCODES) {
        const int c = b;
        const float* e = emb + (size_t)c * DDIM;
        float s = 0.f;
        for (int i = t; i < DDIM; i += 256) { float v = e[i]; s += v * v; }
        for (int off = 32; off; off >>= 1) s += __shfl_down(s, off);
        __shared__ float red[4];
        if ((t & 63) == 0) red[t >> 6] = s;
        __syncthreads();
        if (t == 0) ee[c] = red[0] + red[1] + red[2] + red[3];
        if (t < 192) {
            const float4 v = ((const float4*)e)[t];
            ushort4 h;
            h.x = f2bf(v.x); h.y = f2bf(v.y); h.z = f2bf(v.z); h.w = f2bf(v.w);
            ((ushort4*)(Eh + (size_t)c * DDIM))[t] = h;
        }
    } else {
        const int rb = b - KCODES;
        const int row = rb * 4 + (t >> 6);
        const int lane = t & 63;
        const float* zr = z + (size_t)row * DDIM;
        float s = 0.f;
        for (int i = lane; i < DDIM; i += 64) { float v = zr[i]; s += v * v; }
        for (int off = 32; off; off >>= 1) s += __shfl_down(s, off);
        if (lane == 0) zz[row] = s;
        const float4* zr4 = (const float4*)zr;
        ushort4* dh = (ushort4*)(Zh + (size_t)row * DDIM);
        #pragma unroll
        for (int j = 0; j < 3; ++j) {
            const int i4 = lane + 64 * j;
            const float4 v = zr4[i4];
            ushort4 h;
            h.x = f2bf(v.x); h.y = f2bf(v.y); h.z = f2bf(v.z); h.w = f2bf(v.w);
            dh[i4] = h;
        }
    }
}

// ------ Phase 1: 256x256 tile, 8-wave fine-phase MFMA GEMM, K-slice ring ---
typedef __attribute__((ext_vector_type(8))) short bf16x8;
typedef __attribute__((ext_vector_type(4))) float f32x4;

#define SLOT_SZ 32768          // one 32-k slice: A 256x32 bf16 (16K) + B (16K)
#define BOFF_IN_SLOT 16384
#define NSLICE 24              // 768/32
#define CAPS  8

__global__ __launch_bounds__(512, 2)
void mfma8_kernel(const ushort_t* __restrict__ Ab, const ushort_t* __restrict__ Bb,
                  const float* __restrict__ ee, float* __restrict__ bmin,
                  float2* __restrict__ slots) {
    __shared__ __align__(16) char smem[4 * SLOT_SZ];   // 128 KB ring
    // epilogue aliases (after K-loop only)
    uint_t* rowminU = (uint_t*)smem;                       // 256*4
    int*    rcnt    = (int*)(smem + 1024);                 // 256*4
    float (*sval)[CAPS] = (float(*)[CAPS])(smem + 2048);   // 8KB
    int   (*sidx)[CAPS] = (int(*)[CAPS])(smem + 10240);    // 8KB

    const int t = threadIdx.x;
    const int w = t >> 6, l = t & 63;
    const int bx = blockIdx.x & 63;    // 64 row-blocks
    const int by = blockIdx.x >> 6;    // 8 col-blocks
    const int row0 = bx << 8;          // *256
    const int col0 = by << 8;          // *256

    f32x4 acc[8][4];
    #pragma unroll
    for (int i = 0; i < 8; ++i)
        #pragma unroll
        for (int j = 0; j < 4; ++j) acc[i][j] = (f32x4){0.f, 0.f, 0.f, 0.f};

    // ---- staging maps: linear LDS dest, pre-swizzled global source
    // slice layout per slot: row r (0..255) x 32 k (64 B); byte = r*64 + g'*16,
    // g' = g ^ ((r>>1)&3)  (involution -> pre-swizzle source by same mask)
    size_t gAoff[2], gBoff[2]; uint_t ldsA[2], ldsB[2];
    #pragma unroll
    for (int q = 0; q < 2; ++q) {
        const int r = (w * 2 + q) * 16 + (l >> 2);
        const int gs = (l & 3) ^ ((r >> 1) & 3);
        gAoff[q] = (size_t)(row0 + r) * DDIM + gs * 8;
        gBoff[q] = (size_t)(col0 + r) * DDIM + gs * 8;
        ldsA[q] = (w * 2 + q) * 1024;
        ldsB[q] = BOFF_IN_SLOT + (w * 2 + q) * 1024;
    }

#define STAGE(Sg_) do {                                                        \
        const uint_t sb_ = (uint_t)((Sg_) & 3) * SLOT_SZ;                      \
        const int ko_ = (Sg_) * 32;                                            \
        _Pragma("unroll")                                                      \
        for (int q = 0; q < 2; ++q)                                            \
            __builtin_amdgcn_global_load_lds(                                  \
                (const __attribute__((address_space(1))) void*)(Ab + gAoff[q] + ko_), \
                (__attribute__((address_space(3))) void*)(smem + sb_ + ldsA[q]), \
                16, 0, 0);                                                     \
        _Pragma("unroll")                                                      \
        for (int q = 0; q < 2; ++q)                                            \
            __builtin_amdgcn_global_load_lds(                                  \
                (const __attribute__((address_space(1))) void*)(Bb + gBoff[q] + ko_), \
                (__attribute__((address_space(3))) void*)(smem + sb_ + ldsB[q]), \
                16, 0, 0);                                                     \
    } while (0)

    // ---- fragment LDS byte offsets (slot-relative, loop-invariant)
    const int g = l >> 4, lr = l & 15;
    const int wm = w >> 2, wn = w & 3;     // 2 x 4 wave grid
    int aoff[8], boff[4];
    #pragma unroll
    for (int mi = 0; mi < 8; ++mi) {
        const int r = wm * 128 + mi * 16 + lr;
        aoff[mi] = r * 64 + ((g ^ ((r >> 1) & 3)) << 4);
    }
    #pragma unroll
    for (int ni = 0; ni < 4; ++ni) {
        const int r = wn * 64 + ni * 16 + lr;
        boff[ni] = BOFF_IN_SLOT + r * 64 + ((g ^ ((r >> 1) & 3)) << 4);
    }

    // ---- prologue: slices 0,1 staged; gate slice 0 complete (4 left in flight)
    STAGE(0);
    STAGE(1);
    asm volatile("s_waitcnt vmcnt(4)" ::: "memory");
    __builtin_amdgcn_sched_barrier(0);
    __builtin_amdgcn_s_barrier();
    __builtin_amdgcn_sched_barrier(0);

    // ---- 24 fine phases: read slot S&3, stage slice S+2, 32 MFMA, vmcnt(4)
    for (int S = 0; S < NSLICE; ++S) {
        const char* sb = smem + (uint_t)(S & 3) * SLOT_SZ;
        bf16x8 af[8], bfr[4];
        #pragma unroll
        for (int mi = 0; mi < 8; ++mi) af[mi] = *(const bf16x8*)(sb + aoff[mi]);
        #pragma unroll
        for (int ni = 0; ni < 4; ++ni) bfr[ni] = *(const bf16x8*)(sb + boff[ni]);

        if (S < NSLICE - 2) STAGE(S + 2);

        __builtin_amdgcn_s_setprio(1);
        #pragma unroll
        for (int mi = 0; mi < 8; ++mi)
            #pragma unroll
            for (int ni = 0; ni < 4; ++ni)
                acc[mi][ni] = __builtin_amdgcn_mfma_f32_16x16x32_bf16(
                    af[mi], bfr[ni], acc[mi][ni], 0, 0, 0);
        __builtin_amdgcn_s_setprio(0);

        if (S < NSLICE - 2)       asm volatile("s_waitcnt vmcnt(4)" ::: "memory");
        else if (S == NSLICE - 2) asm volatile("s_waitcnt vmcnt(0)" ::: "memory");
        __builtin_amdgcn_sched_barrier(0);
        __builtin_amdgcn_s_barrier();
        __builtin_amdgcn_sched_barrier(0);
    }
#undef STAGE

    __syncthreads();   // full drain before epilogue aliases smem

    // ---- epilogue: d~ = ee - 2*dot~ (fp32, frozen ops), block-min + slots
    if (t < 256) { rowminU[t] = 0xFFFFFFFFu; rcnt[t] = 0; }
    __syncthreads();

    float ecv[4];
    #pragma unroll
    for (int ni = 0; ni < 4; ++ni) ecv[ni] = ee[col0 + wn * 64 + (ni << 4) + lr];
    #pragma unroll
    for (int mi = 0; mi < 8; ++mi)
        #pragma unroll
        for (int ni = 0; ni < 4; ++ni)
            #pragma unroll
            for (int r = 0; r < 4; ++r)
                acc[mi][ni][r] = ecv[ni] - 2.0f * acc[mi][ni][r];

    #pragma unroll
    for (int mi = 0; mi < 8; ++mi)
        #pragma unroll
        for (int r = 0; r < 4; ++r) {
            float v = acc[mi][0][r];
            #pragma unroll
            for (int ni = 1; ni < 4; ++ni) v = fminf(v, acc[mi][ni][r]);
            v = fminf(v, __shfl_xor(v, 1));
            v = fminf(v, __shfl_xor(v, 2));
            v = fminf(v, __shfl_xor(v, 4));
            v = fminf(v, __shfl_xor(v, 8));
            if (lr == 0)
                atomicMin(&rowminU[wm * 128 + (mi << 4) + (g << 2) + r], fenc(v));
        }
    __syncthreads();

    #pragma unroll
    for (int mi = 0; mi < 8; ++mi)
        #pragma unroll
        for (int r = 0; r < 4; ++r) {
            const int m = wm * 128 + (mi << 4) + (g << 2) + r;
            const float lim = fdec(rowminU[m]) + MARGIN;
            #pragma unroll
            for (int ni = 0; ni < 4; ++ni) {
                const float vv = acc[mi][ni][r];
                if (vv <= lim) {
                    const int p = atomicAdd(&rcnt[m], 1);
                    if (p < CAPS) {
                        sval[m][p] = vv;
                        sidx[m][p] = col0 + wn * 64 + (ni << 4) + lr;
                    }
                }
            }
        }
    __syncthreads();

    if (t < 256) {
        const int row = row0 + t;
        bmin[(size_t)by * NROWS + row] = fdec(rowminU[t]);
        const int n = rcnt[t] < CAPS ? rcnt[t] : CAPS;
        float2 rec[8];
        #pragma unroll
        for (int s2 = 0; s2 < 8; ++s2)
            rec[s2] = (s2 < n) ? make_float2(sval[t][s2], __int_as_float(sidx[t][s2]))
                               : make_float2(FLT_MAX, __int_as_float(0x7fffffff));
        float4* dst = (float4*)(slots + ((size_t)by * NROWS + row) * 8);
        dst[0] = make_float4(rec[0].x, rec[0].y, rec[1].x, rec[1].y);
        dst[1] = make_float4(rec[2].x, rec[2].y, rec[3].x, rec[3].y);
        dst[2] = make_float4(rec[4].x, rec[4].y, rec[5].x, rec[5].y);
        dst[3] = make_float4(rec[6].x, rec[6].y, rec[7].x, rec[7].y);
    }
}

// -- Phase 2: combine + EXACT fp32 re-check (frozen) + gather + loss atomic -
__global__ __launch_bounds__(256)
void combine_select_gather(const float* __restrict__ bmin, const float2* __restrict__ slots,
                           const float* __restrict__ ee, const float* __restrict__ zz,
                           const float* __restrict__ z, const float* __restrict__ emb,
                           float* __restrict__ ids_f32, float* __restrict__ out0,
                           float* __restrict__ out_loss) {
    const int t = threadIdx.x;
    const int w = t >> 6;
    const int row = blockIdx.x * 4 + w;
    const int l = t & 63;

    float v = (l < NCB2) ? bmin[(size_t)l * NROWS + row] : FLT_MAX;
    v = fminf(v, __shfl_xor(v, 4));
    v = fminf(v, __shfl_xor(v, 2));
    v = fminf(v, __shfl_xor(v, 1));
    const float T = __shfl(v, 0) + MARGIN;

    // 64 slots per row (8 blocks x 8) -> exactly one float2 per lane
    const int blk = l >> 3;
    const int s0 = l & 7;
    const float2 a = slots[((size_t)blk * NROWS + row) * 8 + s0];

    unsigned long long m = __ballot(a.x <= T);

    const float* zr = z + (size_t)row * DDIM;
    int bi;
    if (__popcll(m) == 1) {
        // sole survivor is provably the exact argmin (margin >= bf16 bound)
        bi = __float_as_int(__shfl(a.y, __ffsll(m) - 1));
    } else {
        const float zzr = zz[row];
        float bestd = FLT_MAX; int besti = 0x7fffffff;
        while (m) {
            const int j = __ffsll(m) - 1; m &= m - 1;
            const int idx = __float_as_int(__shfl(a.y, j));
            const float* er = emb + (size_t)idx * DDIM;
            float p = 0.f;
            #pragma unroll
            for (int k = 0; k < 12; ++k) p += zr[l + 64 * k] * er[l + 64 * k];
            for (int off = 32; off; off >>= 1) p += __shfl_down(p, off);
            if (l == 0) {
                const float t1 = zzr + ee[idx];     // fp32 round (ref order)
                const float d  = t1 - 2.0f * p;     // fp32 round
                if (d < bestd || (d == bestd && idx < besti)) { bestd = d; besti = idx; }
            }
        }
        bi = __shfl(besti, 0);
    }
    if (l == 0) ids_f32[row] = (float)bi;

    // fused gather + straight-through + loss partial
    const float4* zr4 = (const float4*)zr;
    const float4* er4 = (const float4*)(emb + (size_t)bi * DDIM);
    float4* o4 = (float4*)(out0 + (size_t)row * DDIM);
    float s = 0.f;
    #pragma unroll
    for (int j = 0; j < 3; ++j) {
        const int i4 = l + 64 * j;
        const float4 zv = zr4[i4];
        const float4 ev = er4[i4];
        float4 o;
        o.x = zv.x + (ev.x - zv.x); o.y = zv.y + (ev.y - zv.y);
        o.z = zv.z + (ev.z - zv.z); o.w = zv.w + (ev.w - zv.w);
        o4[i4] = o;
        const float dx = zv.x - ev.x, dy = zv.y - ev.y;
        const float dz = zv.z - ev.z, dw = zv.w - ev.w;
        s += dx * dx + dy * dy + dz * dz + dw * dw;
    }
    for (int off = 32; off; off >>= 1) s += __shfl_down(s, off);
    __shared__ float lred[4];
    if (l == 0) lred[w] = s;
    __syncthreads();
    if (t == 0) {
        const float tot = lred[0] + lred[1] + lred[2] + lred[3];
        atomicAdd(out_loss, tot * (0.25f / (float)((size_t)NROWS * DDIM)));
    }
}

// ================= Fallback (round-3 exact fp32 path, proven) ==============
__global__ void ee_kernel(const float* __restrict__ emb, float* __restrict__ ee) {
    int c = blockIdx.x;
    const float* e = emb + (size_t)c * DDIM;
    int t = threadIdx.x;
    float s = 0.f;
    for (int i = t; i < DDIM; i += 256) { float v = e[i]; s += v * v; }
    for (int off = 32; off; off >>= 1) s += __shfl_down(s, off);
    __shared__ float red[4];
    if ((t & 63) == 0) red[t >> 6] = s;
    __syncthreads();
    if (t == 0) ee[c] = red[0] + red[1] + red[2] + red[3];
}

__global__ void zz_kernel(const float* __restrict__ z, float* __restrict__ zz) {
    const int t = threadIdx.x;
    const int row = blockIdx.x * 4 + (t >> 6);
    const int lane = t & 63;
    const float* zr = z + (size_t)row * DDIM;
    float s = 0.f;
    for (int i = lane; i < DDIM; i += 64) { float v = zr[i]; s += v * v; }
    for (int off = 32; off; off >>= 1) s += __shfl_down(s, off);
    if (lane == 0) zz[row] = s;
}

#define BM 32
#define BN 128
#define BKS 32
#define SPLITC 2
#define CODES_PER_BLOCK (KCODES / SPLITC)
#define NCHUNK (CODES_PER_BLOCK / BN)
#define NSTAGE (DDIM / BKS)
#define APADR 33
#define BPADC 132

__global__ __launch_bounds__(256)
void argmin_kernel(const float* __restrict__ z, const float* __restrict__ emb,
                   const float* __restrict__ ee, const float* __restrict__ zz,
                   float* __restrict__ pval, int* __restrict__ pidx) {
    __shared__ float Af[BKS][APADR];
    __shared__ float Bf[BKS][BPADC];
    __shared__ float cval[BM][33];
    __shared__ int   cidx[BM][33];
    __shared__ float zzs[BM];
    const int t = threadIdx.x;
    const int part = blockIdx.x & (SPLITC - 1);
    const int rb = blockIdx.x >> 1;
    const int row0 = rb * BM;
    const int cbase = part * CODES_PER_BLOCK;
    const int tx = t & 31, ty = t >> 5;
    const int sr = t >> 3;
    const int sk = 4 * (t & 7);
    if (t < BM) zzs[t] = zz[row0 + t];
    float bv[4]; int bi[4];
    #pragma unroll
    for (int i = 0; i < 4; ++i) { bv[i] = FLT_MAX; bi[i] = 0x7fffffff; }
    const float* zt = z + (size_t)(row0 + sr) * DDIM;
    for (int chunk = 0; chunk < NCHUNK; ++chunk) {
        const int c0 = cbase + chunk * BN;
        const float* ebase = emb + (size_t)(c0 + sr) * DDIM;
        float acc[4][4];
        #pragma unroll
        for (int i = 0; i < 4; ++i)
            #pragma unroll
            for (int j = 0; j < 4; ++j) acc[i][j] = 0.f;
        float4 pa = *(const float4*)&zt[sk];
        float4 pb[4];
        #pragma unroll
        for (int m = 0; m < 4; ++m) pb[m] = *(const float4*)&ebase[(size_t)(32 * m) * DDIM + sk];
        for (int s = 0; s < NSTAGE; ++s) {
            __syncthreads();
            Af[sk + 0][sr] = pa.x; Af[sk + 1][sr] = pa.y;
            Af[sk + 2][sr] = pa.z; Af[sk + 3][sr] = pa.w;
            #pragma unroll
            for (int m = 0; m < 4; ++m) {
                Bf[sk + 0][sr + 32 * m] = pb[m].x;
                Bf[sk + 1][sr + 32 * m] = pb[m].y;
                Bf[sk + 2][sr + 32 * m] = pb[m].z;
                Bf[sk + 3][sr + 32 * m] = pb[m].w;
            }
            __syncthreads();
            if (s + 1 < NSTAGE) {
                const int k1 = (s + 1) * BKS + sk;
                pa = *(const float4*)&zt[k1];
                #pragma unroll
                for (int m = 0; m < 4; ++m)
                    pb[m] = *(const float4*)&ebase[(size_t)(32 * m) * DDIM + k1];
            }
            #pragma unroll
            for (int kk = 0; kk < BKS; ++kk) {
                const float4 a4 = *(const float4*)&Af[kk][4 * ty];
                const float4 b4 = *(const float4*)&Bf[kk][4 * tx];
                const float aa[4] = {a4.x, a4.y, a4.z, a4.w};
                const float bb[4] = {b4.x, b4.y, b4.z, b4.w};
                #pragma unroll
                for (int i = 0; i < 4; ++i)
                    #pragma unroll
                    for (int j = 0; j < 4; ++j) acc[i][j] += aa[i] * bb[j];
            }
        }
        const float4 e4 = *(const float4*)&ee[c0 + 4 * tx];
        const float eev[4] = {e4.x, e4.y, e4.z, e4.w};
        #pragma unroll
        for (int i = 0; i < 4; ++i) {
            const float zzr = zzs[4 * ty + i];
            #pragma unroll
            for (int j = 0; j < 4; ++j) {
                const int code = c0 + 4 * tx + j;
                const float t1 = zzr + eev[j];
                const float d  = t1 - 2.0f * acc[i][j];
                if (d < bv[i] || (d == bv[i] && code < bi[i])) { bv[i] = d; bi[i] = code; }
            }
        }
    }
    __syncthreads();
    #pragma unroll
    for (int i = 0; i < 4; ++i) { cval[4 * ty + i][tx] = bv[i]; cidx[4 * ty + i][tx] = bi[i]; }
    __syncthreads();
    if (t < BM) {
        float v = FLT_MAX; int id = 0x7fffffff;
        #pragma unroll
        for (int x = 0; x < 32; ++x) {
            const float cv = cval[t][x]; const int ci = cidx[t][x];
            if (cv < v || (cv == v && ci < id)) { v = cv; id = ci; }
        }
        pval[part * NROWS + row0 + t] = v;
        pidx[part * NROWS + row0 + t] = id;
    }
}

__global__ void combine_kernel(const float* __restrict__ pval, const int* __restrict__ pidx,
                               float* __restrict__ ids_f32) {
    const int r = blockIdx.x * 256 + threadIdx.x;
    float v = pval[r];           int id = pidx[r];
    const float v1 = pval[NROWS + r]; const int i1 = pidx[NROWS + r];
    if (v1 < v || (v1 == v && i1 < id)) { v = v1; id = i1; }
    ids_f32[r] = (float)id;
}

__global__ __launch_bounds__(256)
void gather_kernel(const float* __restrict__ z, const float* __restrict__ emb,
                   const float* __restrict__ ids_f32, float* __restrict__ out0,
                   float* __restrict__ part) {
    const int b = blockIdx.x;
    const int t = threadIdx.x;
    const int rl = t >> 4, c = t & 15;
    __shared__ int ids[16];
    if (t < 16) ids[t] = (int)ids_f32[b * 16 + t];
    __syncthreads();
    const int row = b * 16 + rl;
    const float4* zr = (const float4*)(z + (size_t)row * DDIM);
    float4* orow = (float4*)(out0 + (size_t)row * DDIM);
    const float4* er = (const float4*)(emb + (size_t)ids[rl] * DDIM);
    float s = 0.f;
    #pragma unroll
    for (int j = 0; j < 12; ++j) {
        const int i4 = c + 16 * j;
        const float4 zv = zr[i4];
        const float4 ev = er[i4];
        float4 o;
        o.x = zv.x + (ev.x - zv.x); o.y = zv.y + (ev.y - zv.y);
        o.z = zv.z + (ev.z - zv.z); o.w = zv.w + (ev.w - zv.w);
        orow[i4] = o;
        float dx = zv.x - ev.x, dy = zv.y - ev.y, dz = zv.z - ev.z, dw = zv.w - ev.w;
        s += dx * dx + dy * dy + dz * dz + dw * dw;
    }
    for (int off = 32; off; off >>= 1) s += __shfl_down(s, off);
    __shared__ float red[4];
    if ((t & 63) == 0) red[t >> 6] = s;
    __syncthreads();
    if (t == 0) part[b] = red[0] + red[1] + red[2] + red[3];
}

__global__ void loss_kernel(const float* __restrict__ part, float* __restrict__ out_loss) {
    const int t = threadIdx.x;
    double s = 0.0;
    for (int i = t; i < 1024; i += 256) s += (double)part[i];
    for (int off = 32; off; off >>= 1) s += __shfl_down(s, off);
    __shared__ double red[4];
    if ((t & 63) == 0) red[t >> 6] = s;
    __syncthreads();
    if (t == 0) {
        const double total = red[0] + red[1] + red[2] + red[3];
        out_loss[0] = (float)(0.25 * (total / (double)((size_t)NROWS * DDIM)));
    }
}

// ================= launch ==================================================
#define EE_OFF   0
#define ZZ_OFF   8192
#define EH_OFF   73728
#define ZH_OFF   (EH_OFF + (size_t)KCODES * DDIM * 2)       // +3145728
#define BMIN_OFF (ZH_OFF + (size_t)NROWS * DDIM * 2)        // +25165824
#define SLOT_OFF (BMIN_OFF + (size_t)NCB2 * NROWS * 4)      // +524288
#define WS_NEED  (SLOT_OFF + (size_t)NCB2 * NROWS * 8 * 8)  // ~35.6 MB
#define PART_OFF 73728                                      // fallback (exclusive)
#define PV_OFF   81920

extern "C" void kernel_launch(void* const* d_in, const int* in_sizes, int n_in,
                              void* d_out, int out_size, void* d_ws, size_t ws_size,
                              hipStream_t stream) {
    const float* z   = (const float*)d_in[0];
    const float* emb = (const float*)d_in[1];

    float* out0     = (float*)d_out;
    float* out_ids  = out0 + (size_t)NROWS * DDIM;
    float* out_loss = out_ids + NROWS;

    char* ws = (char*)d_ws;
    float* ee   = (float*)(ws + EE_OFF);
    float* zzws = (float*)(ws + ZZ_OFF);

    if (ws_size >= WS_NEED) {
        ushort_t* Eh   = (ushort_t*)(ws + EH_OFF);
        ushort_t* Zh   = (ushort_t*)(ws + ZH_OFF);
        float*    bmin = (float*)(ws + BMIN_OFF);
        float2*   slot = (float2*)(ws + SLOT_OFF);
        prep_kernel<<<KCODES + NROWS / 4, 256, 0, stream>>>(z, emb, ee, zzws, Zh, Eh, out_loss);
        mfma8_kernel<<<(NROWS / 256) * NCB2, 512, 0, stream>>>(Zh, Eh, ee, bmin, slot);
        combine_select_gather<<<NROWS / 4, 256, 0, stream>>>(bmin, slot, ee, zzws, z, emb,
                                                             out_ids, out0, out_loss);
    } else {
        float* part = (float*)(ws + PART_OFF);
        float* pval = (float*)(ws + PV_OFF);
        int*   pidx = (int*)(ws + PV_OFF + 131072);
        ee_kernel<<<KCODES, 256, 0, stream>>>(emb, ee);
        zz_kernel<<<NROWS / 4, 256, 0, stream>>>(z, zzws);
        argmin_kernel<<<(NROWS / BM) * SPLITC, 256, 0, stream>>>(z, emb, ee, zzws, pval, pidx);
        combine_kernel<<<NROWS / 256, 256, 0, stream>>>(pval, pidx, out_ids);
        gather_kernel<<<NROWS / 16, 256, 0, stream>>>(z, emb, out_ids, out0, part);
        loss_kernel<<<1, 256, 0, stream>>>(part, out_loss);
    }
}

// Round 6
// 239.741 us; speedup vs baseline: 1.1599x; 1.0092x over previous
//
#include <hip/hip_runtime.h>
#include <float.h>

typedef unsigned short ushort_t;
typedef unsigned int uint_t;

// Problem constants
#define NROWS 16384   // 8*2048
#define DDIM  768
#define KCODES 2048
#define NCB2   8      // code blocks (2048/256)
#define MARGIN 8e-4f

// bf16 helpers (RNE)
__device__ __forceinline__ ushort_t f2bf(float x) {
    uint_t u = __float_as_uint(x);
    uint_t r = (u + 0x7fffu + ((u >> 16) & 1u)) >> 16;
    return (ushort_t)r;
}

// monotonic float<->uint encoding for LDS atomicMin on floats
__device__ __forceinline__ uint_t fenc(float f) {
    uint_t u = __float_as_uint(f);
    return (u & 0x80000000u) ? ~u : (u | 0x80000000u);
}
__device__ __forceinline__ float fdec(uint_t k) {
    uint_t u = (k & 0x80000000u) ? (k ^ 0x80000000u) : ~k;
    return __uint_as_float(u);
}

// ---------- prep: ee + zz + bf16 converts + zero loss (round-0 proven) -----
__global__ void prep_kernel(const float* __restrict__ z, const float* __restrict__ emb,
                            float* __restrict__ ee, float* __restrict__ zz,
                            ushort_t* __restrict__ Zh, ushort_t* __restrict__ Eh,
                            float* __restrict__ out_loss) {
    const int b = blockIdx.x, t = threadIdx.x;
    if (b == 0 && t == 0) out_loss[0] = 0.f;
    if (b < KCODES) {
        const int c = b;
        const float* e = emb + (size_t)c * DDIM;
        float s = 0.f;
        for (int i = t; i < DDIM; i += 256) { float v = e[i]; s += v * v; }
        for (int off = 32; off; off >>= 1) s += __shfl_down(s, off);
        __shared__ float red[4];
        if ((t & 63) == 0) red[t >> 6] = s;
        __syncthreads();
        if (t == 0) ee[c] = red[0] + red[1] + red[2] + red[3];
        if (t < 192) {
            const float4 v = ((const float4*)e)[t];
            ushort4 h;
            h.x = f2bf(v.x); h.y = f2bf(v.y); h.z = f2bf(v.z); h.w = f2bf(v.w);
            ((ushort4*)(Eh + (size_t)c * DDIM))[t] = h;
        }
    } else {
        const int rb = b - KCODES;
        const int row = rb * 4 + (t >> 6);
        const int lane = t & 63;
        const float* zr = z + (size_t)row * DDIM;
        float s = 0.f;
        for (int i = lane; i < DDIM; i += 64) { float v = zr[i]; s += v * v; }
        for (int off = 32; off; off >>= 1) s += __shfl_down(s, off);
        if (lane == 0) zz[row] = s;
        const float4* zr4 = (const float4*)zr;
        ushort4* dh = (ushort4*)(Zh + (size_t)row * DDIM);
        #pragma unroll
        for (int j = 0; j < 3; ++j) {
            const int i4 = lane + 64 * j;
            const float4 v = zr4[i4];
            ushort4 h;
            h.x = f2bf(v.x); h.y = f2bf(v.y); h.z = f2bf(v.z); h.w = f2bf(v.w);
            dh[i4] = h;
        }
    }
}

// ------ Phase 1: 256x256 tile, 8-wave fine-phase MFMA GEMM, K-slice ring ---
typedef __attribute__((ext_vector_type(8))) short bf16x8;
typedef __attribute__((ext_vector_type(4))) float f32x4;

#define SLOT_SZ 32768          // one 32-k slice: A 256x32 bf16 (16K) + B (16K)
#define BOFF_IN_SLOT 16384
#define NSLICE 24              // 768/32
#define CAPS  8

__global__ __launch_bounds__(512, 2)
void mfma8_kernel(const ushort_t* __restrict__ Ab, const ushort_t* __restrict__ Bb,
                  const float* __restrict__ ee, float* __restrict__ bmin,
                  float2* __restrict__ slots) {
    __shared__ __align__(16) char smem[4 * SLOT_SZ];   // 128 KB ring
    // epilogue aliases (after K-loop only)
    uint_t* rowminU = (uint_t*)smem;                       // 256*4
    int*    rcnt    = (int*)(smem + 1024);                 // 256*4
    float (*sval)[CAPS] = (float(*)[CAPS])(smem + 2048);   // 8KB
    int   (*sidx)[CAPS] = (int(*)[CAPS])(smem + 10240);    // 8KB

    const int t = threadIdx.x;
    const int w = t >> 6, l = t & 63;
    // XCD-aware decode: blocks round-robin XCDs by id (id%8). Put the 8
    // col-blocks (by=0..7) of the SAME row-panel bx on the SAME XCD,
    // co-resident: per XCD round = 4 A-panels (1.6MB) + Eh (3MB) ~ L2.
    // A-panel then hits L3 once and L2 7x (was: 32 distinct panels/XCD ->
    // 12.6MB working set -> L2 thrash -> 200MB of L3 A-traffic).
    const int id = blockIdx.x;
    const int xcd = id & 7;
    const int j = id >> 3;             // 0..63 per XCD
    const int bx = ((j >> 3) << 3) + xcd;   // 64 row-blocks, 8 per XCD
    const int by = j & 7;              // 8 col-blocks, all co-resident per bx
    const int row0 = bx << 8;          // *256
    const int col0 = by << 8;          // *256

    f32x4 acc[8][4];
    #pragma unroll
    for (int i = 0; i < 8; ++i)
        #pragma unroll
        for (int j2 = 0; j2 < 4; ++j2) acc[i][j2] = (f32x4){0.f, 0.f, 0.f, 0.f};

    // ---- staging maps: linear LDS dest, pre-swizzled global source
    // slice layout per slot: row r (0..255) x 32 k (64 B); byte = r*64 + g'*16,
    // g' = g ^ ((r>>1)&3)  (involution -> pre-swizzle source by same mask)
    size_t gAoff[2], gBoff[2]; uint_t ldsA[2], ldsB[2];
    #pragma unroll
    for (int q = 0; q < 2; ++q) {
        const int r = (w * 2 + q) * 16 + (l >> 2);
        const int gs = (l & 3) ^ ((r >> 1) & 3);
        gAoff[q] = (size_t)(row0 + r) * DDIM + gs * 8;
        gBoff[q] = (size_t)(col0 + r) * DDIM + gs * 8;
        ldsA[q] = (w * 2 + q) * 1024;
        ldsB[q] = BOFF_IN_SLOT + (w * 2 + q) * 1024;
    }

#define STAGE(Sg_) do {                                                        \
        const uint_t sb_ = (uint_t)((Sg_) & 3) * SLOT_SZ;                      \
        const int ko_ = (Sg_) * 32;                                            \
        _Pragma("unroll")                                                      \
        for (int q = 0; q < 2; ++q)                                            \
            __builtin_amdgcn_global_load_lds(                                  \
                (const __attribute__((address_space(1))) void*)(Ab + gAoff[q] + ko_), \
                (__attribute__((address_space(3))) void*)(smem + sb_ + ldsA[q]), \
                16, 0, 0);                                                     \
        _Pragma("unroll")                                                      \
        for (int q = 0; q < 2; ++q)                                            \
            __builtin_amdgcn_global_load_lds(                                  \
                (const __attribute__((address_space(1))) void*)(Bb + gBoff[q] + ko_), \
                (__attribute__((address_space(3))) void*)(smem + sb_ + ldsB[q]), \
                16, 0, 0);                                                     \
    } while (0)

    // ---- fragment LDS byte offsets (slot-relative, loop-invariant)
    const int g = l >> 4, lr = l & 15;
    const int wm = w >> 2, wn = w & 3;     // 2 x 4 wave grid
    int aoff[8], boff[4];
    #pragma unroll
    for (int mi = 0; mi < 8; ++mi) {
        const int r = wm * 128 + mi * 16 + lr;
        aoff[mi] = r * 64 + ((g ^ ((r >> 1) & 3)) << 4);
    }
    #pragma unroll
    for (int ni = 0; ni < 4; ++ni) {
        const int r = wn * 64 + ni * 16 + lr;
        boff[ni] = BOFF_IN_SLOT + r * 64 + ((g ^ ((r >> 1) & 3)) << 4);
    }

    // ---- prologue: slices 0,1 staged; gate slice 0 complete (4 left in flight)
    STAGE(0);
    STAGE(1);
    asm volatile("s_waitcnt vmcnt(4)" ::: "memory");
    __builtin_amdgcn_sched_barrier(0);
    __builtin_amdgcn_s_barrier();
    __builtin_amdgcn_sched_barrier(0);

    // ---- 24 fine phases: read slot S&3, stage slice S+2, 32 MFMA, vmcnt(4)
    for (int S = 0; S < NSLICE; ++S) {
        const char* sb = smem + (uint_t)(S & 3) * SLOT_SZ;
        bf16x8 af[8], bfr[4];
        #pragma unroll
        for (int mi = 0; mi < 8; ++mi) af[mi] = *(const bf16x8*)(sb + aoff[mi]);
        #pragma unroll
        for (int ni = 0; ni < 4; ++ni) bfr[ni] = *(const bf16x8*)(sb + boff[ni]);

        if (S < NSLICE - 2) STAGE(S + 2);

        __builtin_amdgcn_s_setprio(1);
        #pragma unroll
        for (int mi = 0; mi < 8; ++mi)
            #pragma unroll
            for (int ni = 0; ni < 4; ++ni)
                acc[mi][ni] = __builtin_amdgcn_mfma_f32_16x16x32_bf16(
                    af[mi], bfr[ni], acc[mi][ni], 0, 0, 0);
        __builtin_amdgcn_s_setprio(0);

        if (S < NSLICE - 2)       asm volatile("s_waitcnt vmcnt(4)" ::: "memory");
        else if (S == NSLICE - 2) asm volatile("s_waitcnt vmcnt(0)" ::: "memory");
        __builtin_amdgcn_sched_barrier(0);
        __builtin_amdgcn_s_barrier();
        __builtin_amdgcn_sched_barrier(0);
    }
#undef STAGE

    __syncthreads();   // full drain before epilogue aliases smem

    // ---- epilogue: d~ = ee - 2*dot~ (fp32, frozen ops), block-min + slots
    if (t < 256) { rowminU[t] = 0xFFFFFFFFu; rcnt[t] = 0; }
    __syncthreads();

    float ecv[4];
    #pragma unroll
    for (int ni = 0; ni < 4; ++ni) ecv[ni] = ee[col0 + wn * 64 + (ni << 4) + lr];
    #pragma unroll
    for (int mi = 0; mi < 8; ++mi)
        #pragma unroll
        for (int ni = 0; ni < 4; ++ni)
            #pragma unroll
            for (int r = 0; r < 4; ++r)
                acc[mi][ni][r] = ecv[ni] - 2.0f * acc[mi][ni][r];

    #pragma unroll
    for (int mi = 0; mi < 8; ++mi)
        #pragma unroll
        for (int r = 0; r < 4; ++r) {
            float v = acc[mi][0][r];
            #pragma unroll
            for (int ni = 1; ni < 4; ++ni) v = fminf(v, acc[mi][ni][r]);
            v = fminf(v, __shfl_xor(v, 1));
            v = fminf(v, __shfl_xor(v, 2));
            v = fminf(v, __shfl_xor(v, 4));
            v = fminf(v, __shfl_xor(v, 8));
            if (lr == 0)
                atomicMin(&rowminU[wm * 128 + (mi << 4) + (g << 2) + r], fenc(v));
        }
    __syncthreads();

    #pragma unroll
    for (int mi = 0; mi < 8; ++mi)
        #pragma unroll
        for (int r = 0; r < 4; ++r) {
            const int m = wm * 128 + (mi << 4) + (g << 2) + r;
            const float lim = fdec(rowminU[m]) + MARGIN;
            #pragma unroll
            for (int ni = 0; ni < 4; ++ni) {
                const float vv = acc[mi][ni][r];
                if (vv <= lim) {
                    const int p = atomicAdd(&rcnt[m], 1);
                    if (p < CAPS) {
                        sval[m][p] = vv;
                        sidx[m][p] = col0 + wn * 64 + (ni << 4) + lr;
                    }
                }
            }
        }
    __syncthreads();

    if (t < 256) {
        const int row = row0 + t;
        bmin[(size_t)by * NROWS + row] = fdec(rowminU[t]);
        const int n = rcnt[t] < CAPS ? rcnt[t] : CAPS;
        float2 rec[8];
        #pragma unroll
        for (int s2 = 0; s2 < 8; ++s2)
            rec[s2] = (s2 < n) ? make_float2(sval[t][s2], __int_as_float(sidx[t][s2]))
                               : make_float2(FLT_MAX, __int_as_float(0x7fffffff));
        float4* dst = (float4*)(slots + ((size_t)by * NROWS + row) * 8);
        dst[0] = make_float4(rec[0].x, rec[0].y, rec[1].x, rec[1].y);
        dst[1] = make_float4(rec[2].x, rec[2].y, rec[3].x, rec[3].y);
        dst[2] = make_float4(rec[4].x, rec[4].y, rec[5].x, rec[5].y);
        dst[3] = make_float4(rec[6].x, rec[6].y, rec[7].x, rec[7].y);
    }
}

// -- Phase 2: combine + EXACT fp32 re-check (frozen) + gather + loss atomic -
__global__ __launch_bounds__(256)
void combine_select_gather(const float* __restrict__ bmin, const float2* __restrict__ slots,
                           const float* __restrict__ ee, const float* __restrict__ zz,
                           const float* __restrict__ z, const float* __restrict__ emb,
                           float* __restrict__ ids_f32, float* __restrict__ out0,
                           float* __restrict__ out_loss) {
    const int t = threadIdx.x;
    const int w = t >> 6;
    const int row = blockIdx.x * 4 + w;
    const int l = t & 63;

    float v = (l < NCB2) ? bmin[(size_t)l * NROWS + row] : FLT_MAX;
    v = fminf(v, __shfl_xor(v, 4));
    v = fminf(v, __shfl_xor(v, 2));
    v = fminf(v, __shfl_xor(v, 1));
    const float T = __shfl(v, 0) + MARGIN;

    // 64 slots per row (8 blocks x 8) -> exactly one float2 per lane
    const int blk = l >> 3;
    const int s0 = l & 7;
    const float2 a = slots[((size_t)blk * NROWS + row) * 8 + s0];

    unsigned long long m = __ballot(a.x <= T);

    const float* zr = z + (size_t)row * DDIM;
    int bi;
    if (__popcll(m) == 1) {
        // sole survivor is provably the exact argmin (margin >= bf16 bound)
        bi = __float_as_int(__shfl(a.y, __ffsll(m) - 1));
    } else {
        const float zzr = zz[row];
        float bestd = FLT_MAX; int besti = 0x7fffffff;
        while (m) {
            const int j = __ffsll(m) - 1; m &= m - 1;
            const int idx = __float_as_int(__shfl(a.y, j));
            const float* er = emb + (size_t)idx * DDIM;
            float p = 0.f;
            #pragma unroll
            for (int k = 0; k < 12; ++k) p += zr[l + 64 * k] * er[l + 64 * k];
            for (int off = 32; off; off >>= 1) p += __shfl_down(p, off);
            if (l == 0) {
                const float t1 = zzr + ee[idx];     // fp32 round (ref order)
                const float d  = t1 - 2.0f * p;     // fp32 round
                if (d < bestd || (d == bestd && idx < besti)) { bestd = d; besti = idx; }
            }
        }
        bi = __shfl(besti, 0);
    }
    if (l == 0) ids_f32[row] = (float)bi;

    // fused gather + straight-through + loss partial
    const float4* zr4 = (const float4*)zr;
    const float4* er4 = (const float4*)(emb + (size_t)bi * DDIM);
    float4* o4 = (float4*)(out0 + (size_t)row * DDIM);
    float s = 0.f;
    #pragma unroll
    for (int j = 0; j < 3; ++j) {
        const int i4 = l + 64 * j;
        const float4 zv = zr4[i4];
        const float4 ev = er4[i4];
        float4 o;
        o.x = zv.x + (ev.x - zv.x); o.y = zv.y + (ev.y - zv.y);
        o.z = zv.z + (ev.z - zv.z); o.w = zv.w + (ev.w - zv.w);
        o4[i4] = o;
        const float dx = zv.x - ev.x, dy = zv.y - ev.y;
        const float dz = zv.z - ev.z, dw = zv.w - ev.w;
        s += dx * dx + dy * dy + dz * dz + dw * dw;
    }
    for (int off = 32; off; off >>= 1) s += __shfl_down(s, off);
    __shared__ float lred[4];
    if (l == 0) lred[w] = s;
    __syncthreads();
    if (t == 0) {
        const float tot = lred[0] + lred[1] + lred[2] + lred[3];
        atomicAdd(out_loss, tot * (0.25f / (float)((size_t)NROWS * DDIM)));
    }
}

// ================= Fallback (round-3 exact fp32 path, proven) ==============
__global__ void ee_kernel(const float* __restrict__ emb, float* __restrict__ ee) {
    int c = blockIdx.x;
    const float* e = emb + (size_t)c * DDIM;
    int t = threadIdx.x;
    float s = 0.f;
    for (int i = t; i < DDIM; i += 256) { float v = e[i]; s += v * v; }
    for (int off = 32; off; off >>= 1) s += __shfl_down(s, off);
    __shared__ float red[4];
    if ((t & 63) == 0) red[t >> 6] = s;
    __syncthreads();
    if (t == 0) ee[c] = red[0] + red[1] + red[2] + red[3];
}

__global__ void zz_kernel(const float* __restrict__ z, float* __restrict__ zz) {
    const int t = threadIdx.x;
    const int row = blockIdx.x * 4 + (t >> 6);
    const int lane = t & 63;
    const float* zr = z + (size_t)row * DDIM;
    float s = 0.f;
    for (int i = lane; i < DDIM; i += 64) { float v = zr[i]; s += v * v; }
    for (int off = 32; off; off >>= 1) s += __shfl_down(s, off);
    if (lane == 0) zz[row] = s;
}

#define BM 32
#define BN 128
#define BKS 32
#define SPLITC 2
#define CODES_PER_BLOCK (KCODES / SPLITC)
#define NCHUNK (CODES_PER_BLOCK / BN)
#define NSTAGE (DDIM / BKS)
#define APADR 33
#define BPADC 132

__global__ __launch_bounds__(256)
void argmin_kernel(const float* __restrict__ z, const float* __restrict__ emb,
                   const float* __restrict__ ee, const float* __restrict__ zz,
                   float* __restrict__ pval, int* __restrict__ pidx) {
    __shared__ float Af[BKS][APADR];
    __shared__ float Bf[BKS][BPADC];
    __shared__ float cval[BM][33];
    __shared__ int   cidx[BM][33];
    __shared__ float zzs[BM];
    const int t = threadIdx.x;
    const int part = blockIdx.x & (SPLITC - 1);
    const int rb = blockIdx.x >> 1;
    const int row0 = rb * BM;
    const int cbase = part * CODES_PER_BLOCK;
    const int tx = t & 31, ty = t >> 5;
    const int sr = t >> 3;
    const int sk = 4 * (t & 7);
    if (t < BM) zzs[t] = zz[row0 + t];
    float bv[4]; int bi[4];
    #pragma unroll
    for (int i = 0; i < 4; ++i) { bv[i] = FLT_MAX; bi[i] = 0x7fffffff; }
    const float* zt = z + (size_t)(row0 + sr) * DDIM;
    for (int chunk = 0; chunk < NCHUNK; ++chunk) {
        const int c0 = cbase + chunk * BN;
        const float* ebase = emb + (size_t)(c0 + sr) * DDIM;
        float acc[4][4];
        #pragma unroll
        for (int i = 0; i < 4; ++i)
            #pragma unroll
            for (int j = 0; j < 4; ++j) acc[i][j] = 0.f;
        float4 pa = *(const float4*)&zt[sk];
        float4 pb[4];
        #pragma unroll
        for (int m = 0; m < 4; ++m) pb[m] = *(const float4*)&ebase[(size_t)(32 * m) * DDIM + sk];
        for (int s = 0; s < NSTAGE; ++s) {
            __syncthreads();
            Af[sk + 0][sr] = pa.x; Af[sk + 1][sr] = pa.y;
            Af[sk + 2][sr] = pa.z; Af[sk + 3][sr] = pa.w;
            #pragma unroll
            for (int m = 0; m < 4; ++m) {
                Bf[sk + 0][sr + 32 * m] = pb[m].x;
                Bf[sk + 1][sr + 32 * m] = pb[m].y;
                Bf[sk + 2][sr + 32 * m] = pb[m].z;
                Bf[sk + 3][sr + 32 * m] = pb[m].w;
            }
            __syncthreads();
            if (s + 1 < NSTAGE) {
                const int k1 = (s + 1) * BKS + sk;
                pa = *(const float4*)&zt[k1];
                #pragma unroll
                for (int m = 0; m < 4; ++m)
                    pb[m] = *(const float4*)&ebase[(size_t)(32 * m) * DDIM + k1];
            }
            #pragma unroll
            for (int kk = 0; kk < BKS; ++kk) {
                const float4 a4 = *(const float4*)&Af[kk][4 * ty];
                const float4 b4 = *(const float4*)&Bf[kk][4 * tx];
                const float aa[4] = {a4.x, a4.y, a4.z, a4.w};
                const float bb[4] = {b4.x, b4.y, b4.z, b4.w};
                #pragma unroll
                for (int i = 0; i < 4; ++i)
                    #pragma unroll
                    for (int j = 0; j < 4; ++j) acc[i][j] += aa[i] * bb[j];
            }
        }
        const float4 e4 = *(const float4*)&ee[c0 + 4 * tx];
        const float eev[4] = {e4.x, e4.y, e4.z, e4.w};
        #pragma unroll
        for (int i = 0; i < 4; ++i) {
            const float zzr = zzs[4 * ty + i];
            #pragma unroll
            for (int j = 0; j < 4; ++j) {
                const int code = c0 + 4 * tx + j;
                const float t1 = zzr + eev[j];
                const float d  = t1 - 2.0f * acc[i][j];
                if (d < bv[i] || (d == bv[i] && code < bi[i])) { bv[i] = d; bi[i] = code; }
            }
        }
    }
    __syncthreads();
    #pragma unroll
    for (int i = 0; i < 4; ++i) { cval[4 * ty + i][tx] = bv[i]; cidx[4 * ty + i][tx] = bi[i]; }
    __syncthreads();
    if (t < BM) {
        float v = FLT_MAX; int id = 0x7fffffff;
        #pragma unroll
        for (int x = 0; x < 32; ++x) {
            const float cv = cval[t][x]; const int ci = cidx[t][x];
            if (cv < v || (cv == v && ci < id)) { v = cv; id = ci; }
        }
        pval[part * NROWS + row0 + t] = v;
        pidx[part * NROWS + row0 + t] = id;
    }
}

__global__ void combine_kernel(const float* __restrict__ pval, const int* __restrict__ pidx,
                               float* __restrict__ ids_f32) {
    const int r = blockIdx.x * 256 + threadIdx.x;
    float v = pval[r];           int id = pidx[r];
    const float v1 = pval[NROWS + r]; const int i1 = pidx[NROWS + r];
    if (v1 < v || (v1 == v && i1 < id)) { v = v1; id = i1; }
    ids_f32[r] = (float)id;
}

__global__ __launch_bounds__(256)
void gather_kernel(const float* __restrict__ z, const float* __restrict__ emb,
                   const float* __restrict__ ids_f32, float* __restrict__ out0,
                   float* __restrict__ part) {
    const int b = blockIdx.x;
    const int t = threadIdx.x;
    const int rl = t >> 4, c = t & 15;
    __shared__ int ids[16];
    if (t < 16) ids[t] = (int)ids_f32[b * 16 + t];
    __syncthreads();
    const int row = b * 16 + rl;
    const float4* zr = (const float4*)(z + (size_t)row * DDIM);
    float4* orow = (float4*)(out0 + (size_t)row * DDIM);
    const float4* er = (const float4*)(emb + (size_t)ids[rl] * DDIM);
    float s = 0.f;
    #pragma unroll
    for (int j = 0; j < 12; ++j) {
        const int i4 = c + 16 * j;
        const float4 zv = zr[i4];
        const float4 ev = er[i4];
        float4 o;
        o.x = zv.x + (ev.x - zv.x); o.y = zv.y + (ev.y - zv.y);
        o.z = zv.z + (ev.z - zv.z); o.w = zv.w + (ev.w - zv.w);
        orow[i4] = o;
        float dx = zv.x - ev.x, dy = zv.y - ev.y, dz = zv.z - ev.z, dw = zv.w - ev.w;
        s += dx * dx + dy * dy + dz * dz + dw * dw;
    }
    for (int off = 32; off; off >>= 1) s += __shfl_down(s, off);
    __shared__ float red[4];
    if ((t & 63) == 0) red[t >> 6] = s;
    __syncthreads();
    if (t == 0) part[b] = red[0] + red[1] + red[2] + red[3];
}

__global__ void loss_kernel(const float* __restrict__ part, float* __restrict__ out_loss) {
    const int t = threadIdx.x;
    double s = 0.0;
    for (int i = t; i < 1024; i += 256) s += (double)part[i];
    for (int off = 32; off; off >>= 1) s += __shfl_down(s, off);
    __shared__ double red[4];
    if ((t & 63) == 0) red[t >> 6] = s;
    __syncthreads();
    if (t == 0) {
        const double total = red[0] + red[1] + red[2] + red[3];
        out_loss[0] = (float)(0.25 * (total / (double)((size_t)NROWS * DDIM)));
    }
}

// ================= launch ==================================================
#define EE_OFF   0
#define ZZ_OFF   8192
#define EH_OFF   73728
#define ZH_OFF   (EH_OFF + (size_t)KCODES * DDIM * 2)       // +3145728
#define BMIN_OFF (ZH_OFF + (size_t)NROWS * DDIM * 2)        // +25165824
#define SLOT_OFF (BMIN_OFF + (size_t)NCB2 * NROWS * 4)      // +524288
#define WS_NEED  (SLOT_OFF + (size_t)NCB2 * NROWS * 8 * 8)  // ~35.6 MB
#define PART_OFF 73728                                      // fallback (exclusive)
#define PV_OFF   81920

extern "C" void kernel_launch(void* const* d_in, const int* in_sizes, int n_in,
                              void* d_out, int out_size, void* d_ws, size_t ws_size,
                              hipStream_t stream) {
    const float* z   = (const float*)d_in[0];
    const float* emb = (const float*)d_in[1];

    float* out0     = (float*)d_out;
    float* out_ids  = out0 + (size_t)NROWS * DDIM;
    float* out_loss = out_ids + NROWS;

    char* ws = (char*)d_ws;
    float* ee   = (float*)(ws + EE_OFF);
    float* zzws = (float*)(ws + ZZ_OFF);

    if (ws_size >= WS_NEED) {
        ushort_t* Eh   = (ushort_t*)(ws + EH_OFF);
        ushort_t* Zh   = (ushort_t*)(ws + ZH_OFF);
        float*    bmin = (float*)(ws + BMIN_OFF);
        float2*   slot = (float2*)(ws + SLOT_OFF);
        prep_kernel<<<KCODES + NROWS / 4, 256, 0, stream>>>(z, emb, ee, zzws, Zh, Eh, out_loss);
        mfma8_kernel<<<(NROWS / 256) * NCB2, 512, 0, stream>>>(Zh, Eh, ee, bmin, slot);
        combine_select_gather<<<NROWS / 4, 256, 0, stream>>>(bmin, slot, ee, zzws, z, emb,
                                                             out_ids, out0, out_loss);
    } else {
        float* part = (float*)(ws + PART_OFF);
        float* pval = (float*)(ws + PV_OFF);
        int*   pidx = (int*)(ws + PV_OFF + 131072);
        ee_kernel<<<KCODES, 256, 0, stream>>>(emb, ee);
        zz_kernel<<<NROWS / 4, 256, 0, stream>>>(z, zzws);
        argmin_kernel<<<(NROWS / BM) * SPLITC, 256, 0, stream>>>(z, emb, ee, zzws, pval, pidx);
        combine_kernel<<<NROWS / 256, 256, 0, stream>>>(pval, pidx, out_ids);
        gather_kernel<<<NROWS / 16, 256, 0, stream>>>(z, emb, out_ids, out0, part);
        loss_kernel<<<1, 256, 0, stream>>>(part, out_loss);
    }
}